// Round 2
// baseline (937.152 us; speedup 1.0000x reference)
//
#include <hip/hip_runtime.h>
#include <math.h>

#define B_   16
#define V_   16
#define C_   64
#define M_   32
#define CM_  16
#define D_   128
#define OUT_ 600
#define NSEQ 256      // B*V
#define NROW 8192     // B*V*M

// ---- workspace layout (floats) ----
constexpr int OFF_VIS   = 0;                              // [3][256][128]
constexpr int OFF_MON   = OFF_VIS   + 3*NSEQ*D_;          // [2][8192][128]
constexpr int OFF_W12   = OFF_MON   + 2*NROW*D_;          // [2][4][2][128][128]
constexpr int OFF_WIHTM = OFF_W12   + 2*4*2*D_*D_;        // [5][128][384]
constexpr int OFF_WIHTV = OFF_WIHTM + 5*D_*384;           // [4][128][384]
constexpr int OFF_XE    = OFF_WIHTV + 4*D_*384;           // [2][256][128]
constexpr int OFF_GNN   = OFF_XE    + 2*NSEQ*D_;          // [8][8192][128]
constexpr int OFF_GI    = OFF_GNN   + 8*NROW*D_;          // [8][8192][384]
constexpr int OFF_LAST  = OFF_GI    + 8*NROW*384;         // [8][256][128]
constexpr int OFF_VGI   = OFF_LAST  + 8*NSEQ*D_;          // [10][256][384]
constexpr int OFF_VH    = OFF_VGI   + 10*NSEQ*384;        // [10][16][128]

// =====================================================================
// prep: combined GNN weights, transposed Wih (monitor+visit), weight/age xe
// =====================================================================
__global__ __launch_bounds__(256) void k_prep(
    const float* __restrict__ Wself, const float* __restrict__ Wmsg,
    const float* __restrict__ mWih,  const float* __restrict__ vWih,
    const float* __restrict__ wgt,   const float* __restrict__ age,
    const float* __restrict__ fwW,   const float* __restrict__ fwB,
    const float* __restrict__ faW,   const float* __restrict__ faB,
    float* __restrict__ w12, float* __restrict__ wihTm,
    float* __restrict__ wihTv, float* __restrict__ xe)
{
  int bx = blockIdx.x, tid = threadIdx.x;
  if (bx < 512) {                       // W1 = Wself - Wmsg/3 ; W2 = Wmsg/3
    int lin = bx*256 + tid;             // < 131072
    int pt = lin >> 14, rem = lin & 16383;
    float wsv = Wself[pt*16384 + rem];
    float wmv = Wmsg [pt*16384 + rem];
    w12[(pt*2+0)*16384 + rem] = wsv - wmv*(1.f/3.f);
    w12[(pt*2+1)*16384 + rem] = wmv*(1.f/3.f);
  } else if (bx < 1472) {               // mgru Wih transpose [g][k][j]
    int lin = (bx-512)*256 + tid;       // < 245760
    int g = lin / 49152, rem = lin % 49152;
    int k = rem / 384, j = rem % 384;
    wihTm[lin] = mWih[g*49152 + j*128 + k];
  } else if (bx < 2240) {               // vgru Wih transpose
    int lin = (bx-1472)*256 + tid;      // < 196608
    int g = lin / 49152, rem = lin % 49152;
    int k = rem / 384, j = rem % 384;
    wihTv[lin] = vWih[g*49152 + j*128 + k];
  } else {                              // xe for weight / age
    int lin = (bx-2240)*256 + tid;      // < 65536
    int which = lin >> 15, rem = lin & 32767;
    int n = rem >> 7, d = rem & 127;
    float x  = which ? age[n] : wgt[n];
    float Wv = which ? faW[d] : fwW[d];
    float bb = which ? faB[d] : fwB[d];
    xe[lin] = (x != 0.0f) ? (x*Wv + bb) : 0.0f;
  }
}

// =====================================================================
// visit-event embedding sum pools: vis[type][bv][d]
// =====================================================================
__global__ __launch_bounds__(128) void k_vis(
    const int* __restrict__ cc, const int* __restrict__ cp, const int* __restrict__ cd,
    const float* __restrict__ ec, const float* __restrict__ ep, const float* __restrict__ ed,
    float* __restrict__ vis)
{
  int type = blockIdx.x >> 8;
  int bv   = blockIdx.x & 255;
  int d    = threadIdx.x;
  const int*   codes = (type==0) ? cc : (type==1) ? cp : cd;
  const float* emb   = (type==0) ? ec : (type==1) ? ep : ed;
  float acc = 0.f;
  for (int c = 0; c < C_; ++c) {
    int code = codes[bv*C_ + c];
    acc += emb[code*D_ + d];
  }
  vis[(type*NSEQ + bv)*D_ + d] = acc;
}

// =====================================================================
// monitor-event pools: mon[p][bvm][d] = sum_c ei[ci]*ev[cv]
// =====================================================================
__global__ __launch_bounds__(128) void k_mon(
    const int* __restrict__ cli, const int* __restrict__ clv,
    const int* __restrict__ cii, const int* __restrict__ civ,
    const float* __restrict__ eli, const float* __restrict__ elv,
    const float* __restrict__ eii, const float* __restrict__ eiv,
    float* __restrict__ mon)
{
  int p   = blockIdx.x >> 13;
  int bvm = blockIdx.x & 8191;
  int d   = threadIdx.x;
  const int* ci = p ? cii : cli;  const int* cv = p ? civ : clv;
  const float* ei = p ? eii : eli; const float* ev = p ? eiv : elv;
  float acc = 0.f;
  #pragma unroll
  for (int c = 0; c < CM_; ++c) {
    int iv = ci[bvm*CM_ + c];
    int vv = cv[bvm*CM_ + c];
    acc += ei[iv*D_ + d] * ev[vv*D_ + d];
  }
  mon[(p*NROW + bvm)*D_ + d] = acc;
}

// =====================================================================
// GNN: out[pt] = relu( feat@W1 + total@W2 )  as one K=256 GEMM
// tile: 128 rows x 128 cols, 256 threads, 8x8 per thread
// =====================================================================
__global__ __launch_bounds__(256) void k_gnn(
    const float* __restrict__ vis, const float* __restrict__ mon,
    const float* __restrict__ w12, float* __restrict__ out)
{
  int pt   = blockIdx.x >> 6;
  int mblk = blockIdx.x & 63;
  int p = pt >> 2, t = pt & 3;
  int m0 = mblk * 128;
  int tid = threadIdx.x;
  __shared__ __align__(16) float Xs[32][132];
  __shared__ __align__(16) float Ws[32][132];
  float acc[8][8];
  #pragma unroll
  for (int i = 0; i < 8; ++i)
    #pragma unroll
    for (int jj = 0; jj < 8; ++jj) acc[i][jj] = 0.f;

  int tc = tid & 15, tr = tid >> 4;
  int kkS = tid & 31, rrS = tid >> 5;
  int cS  = tid & 127, kwS = tid >> 7;

  const float* monp = mon + p*NROW*D_;
  const float* visA = vis;
  const float* visB = vis + NSEQ*D_;
  const float* visC = vis + 2*NSEQ*D_;
  const float* featv = (t > 0) ? (vis + (t-1)*NSEQ*D_) : monp;

  for (int ks = 0; ks < 8; ++ks) {
    #pragma unroll
    for (int pass = 0; pass < 16; ++pass) {
      int r = rrS + pass*8;
      int row = m0 + r;
      int bv = row >> 5;
      int k = ks*32 + kkS;
      float v;
      if (k < 128) {
        v = (t == 0) ? monp[row*D_ + k] : featv[bv*D_ + k];
      } else {
        int k2 = k - 128;
        v = monp[row*D_ + k2] + visA[bv*D_ + k2] + visB[bv*D_ + k2] + visC[bv*D_ + k2];
      }
      Xs[kkS][r] = v;
    }
    #pragma unroll
    for (int pass = 0; pass < 16; ++pass) {
      int kk = kwS + pass*2;
      int k = ks*32 + kk;
      int which = (k >= 128) ? 1 : 0;
      Ws[kk][cS] = w12[((pt*2 + which)*128 + (k & 127))*128 + cS];
    }
    __syncthreads();
    #pragma unroll
    for (int kk = 0; kk < 32; ++kk) {
      float4 a0 = *(const float4*)&Xs[kk][tr*4];
      float4 a1 = *(const float4*)&Xs[kk][64 + tr*4];
      float4 b0 = *(const float4*)&Ws[kk][tc*4];
      float4 b1 = *(const float4*)&Ws[kk][64 + tc*4];
      float av[8] = {a0.x,a0.y,a0.z,a0.w,a1.x,a1.y,a1.z,a1.w};
      float bw[8] = {b0.x,b0.y,b0.z,b0.w,b1.x,b1.y,b1.z,b1.w};
      #pragma unroll
      for (int i = 0; i < 8; ++i)
        #pragma unroll
        for (int jj = 0; jj < 8; ++jj)
          acc[i][jj] += av[i]*bw[jj];
    }
    __syncthreads();
  }
  float* op = out + pt*NROW*D_;
  #pragma unroll
  for (int i = 0; i < 8; ++i) {
    int ri = (i < 4) ? (tr*4 + i) : (64 + tr*4 + i - 4);
    float4 v0 = make_float4(fmaxf(acc[i][0],0.f), fmaxf(acc[i][1],0.f),
                            fmaxf(acc[i][2],0.f), fmaxf(acc[i][3],0.f));
    float4 v1 = make_float4(fmaxf(acc[i][4],0.f), fmaxf(acc[i][5],0.f),
                            fmaxf(acc[i][6],0.f), fmaxf(acc[i][7],0.f));
    *(float4*)&op[(m0+ri)*D_ + tc*4] = v0;
    *(float4*)&op[(m0+ri)*D_ + 64 + tc*4] = v1;
  }
}

// =====================================================================
// gi precompute: gi[run][row][j] = gnn_out[run] @ WihT[g] + bih[g]
// =====================================================================
__global__ __launch_bounds__(256) void k_gi(
    const float* __restrict__ gnn, const float* __restrict__ wihTm,
    const float* __restrict__ mbih, float* __restrict__ gi)
{
  int bx = blockIdx.x;
  int run = bx / 192, rem = bx % 192;
  int mblk = rem / 3, nblk = rem % 3;
  int g = (run % 4 == 0) ? (run / 4) : (run % 4 + 1);
  int m0 = mblk * 128;
  int tid = threadIdx.x;
  __shared__ __align__(16) float Xs[32][132];
  __shared__ __align__(16) float Ws[32][132];
  float acc[8][8];
  #pragma unroll
  for (int i = 0; i < 8; ++i)
    #pragma unroll
    for (int jj = 0; jj < 8; ++jj) acc[i][jj] = 0.f;

  int tc = tid & 15, tr = tid >> 4;
  int kkS = tid & 31, rrS = tid >> 5;
  int cS  = tid & 127, kwS = tid >> 7;

  const float* X = gnn + run*NROW*D_;
  const float* W = wihTm + g*49152 + nblk*128;

  for (int ks = 0; ks < 4; ++ks) {
    #pragma unroll
    for (int pass = 0; pass < 16; ++pass) {
      int r = rrS + pass*8;
      Xs[kkS][r] = X[(m0 + r)*D_ + ks*32 + kkS];
    }
    #pragma unroll
    for (int pass = 0; pass < 16; ++pass) {
      int kk = kwS + pass*2;
      Ws[kk][cS] = W[(ks*32 + kk)*384 + cS];
    }
    __syncthreads();
    #pragma unroll
    for (int kk = 0; kk < 32; ++kk) {
      float4 a0 = *(const float4*)&Xs[kk][tr*4];
      float4 a1 = *(const float4*)&Xs[kk][64 + tr*4];
      float4 b0 = *(const float4*)&Ws[kk][tc*4];
      float4 b1 = *(const float4*)&Ws[kk][64 + tc*4];
      float av[8] = {a0.x,a0.y,a0.z,a0.w,a1.x,a1.y,a1.z,a1.w};
      float bw[8] = {b0.x,b0.y,b0.z,b0.w,b1.x,b1.y,b1.z,b1.w};
      #pragma unroll
      for (int i = 0; i < 8; ++i)
        #pragma unroll
        for (int jj = 0; jj < 8; ++jj)
          acc[i][jj] += av[i]*bw[jj];
    }
    __syncthreads();
  }
  const float* bb = mbih + g*384 + nblk*128;
  float4 bb0 = *(const float4*)&bb[tc*4];
  float4 bb1 = *(const float4*)&bb[64 + tc*4];
  #pragma unroll
  for (int i = 0; i < 8; ++i) {
    int ri = (i < 4) ? (tr*4 + i) : (64 + tr*4 + i - 4);
    float* rowp = gi + (run*NROW + m0 + ri)*384 + nblk*128;
    float4 v0 = make_float4(acc[i][0]+bb0.x, acc[i][1]+bb0.y, acc[i][2]+bb0.z, acc[i][3]+bb0.w);
    float4 v1 = make_float4(acc[i][4]+bb1.x, acc[i][5]+bb1.y, acc[i][6]+bb1.z, acc[i][7]+bb1.w);
    *(float4*)&rowp[tc*4] = v0;
    *(float4*)&rowp[64 + tc*4] = v1;
  }
}

// =====================================================================
// monitor-level GRU v2: 8 runs x 64 groups of 4 seqs = 512 blocks
// (2 blocks/CU, all resident). 384 threads, Whh row register-resident.
// Dot product split into 4 independent partial chains for ILP.
// =====================================================================
__global__ __launch_bounds__(384, 3) void k_mgru(
    const float* __restrict__ gi, const float* __restrict__ mWhh,
    const float* __restrict__ mbhh, float* __restrict__ last)
{
  int run = blockIdx.x >> 6, grp = blockIdx.x & 63;
  int j = threadIdx.x;
  int g = (run % 4 == 0) ? (run / 4) : (run % 4 + 1);
  float w[128];
  const float4* wrow = (const float4*)(mWhh + (g*384 + j)*128);
  #pragma unroll
  for (int k4 = 0; k4 < 32; ++k4) {
    float4 tt = wrow[k4];
    w[4*k4] = tt.x; w[4*k4+1] = tt.y; w[4*k4+2] = tt.z; w[4*k4+3] = tt.w;
  }
  float bj = mbhh[g*384 + j];
  __shared__ __align__(16) float hs[4][128];
  __shared__ float ghs[4][384];
  for (int idx = j; idx < 512; idx += 384) hs[idx >> 7][idx & 127] = 0.f;
  __syncthreads();
  const float* gib = gi + (run*NROW + grp*128)*384;   // 4 seqs * 32 steps rows
  #pragma unroll 1
  for (int m = 0; m < 32; ++m) {
    #pragma unroll 1
    for (int s = 0; s < 4; ++s) {
      float gval = (j < 256) ? gib[(s*32 + m)*384 + j] : 0.f;
      const float4* h4 = (const float4*)hs[s];
      float p0 = 0.f, p1 = 0.f, p2 = 0.f, p3 = 0.f;
      #pragma unroll
      for (int k4 = 0; k4 < 8; ++k4) {
        float4 u0 = h4[k4], u1 = h4[k4+8], u2 = h4[k4+16], u3 = h4[k4+24];
        p0 += w[4*k4   ]*u0.x + w[4*k4+1 ]*u0.y + w[4*k4+2 ]*u0.z + w[4*k4+3 ]*u0.w;
        p1 += w[4*k4+32]*u1.x + w[4*k4+33]*u1.y + w[4*k4+34]*u1.z + w[4*k4+35]*u1.w;
        p2 += w[4*k4+64]*u2.x + w[4*k4+65]*u2.y + w[4*k4+66]*u2.z + w[4*k4+67]*u2.w;
        p3 += w[4*k4+96]*u3.x + w[4*k4+97]*u3.y + w[4*k4+98]*u3.z + w[4*k4+99]*u3.w;
      }
      ghs[s][j] = bj + gval + (p0 + p1) + (p2 + p3);
    }
    __syncthreads();
    if (j < 128) {
      #pragma unroll
      for (int s = 0; s < 4; ++s) {
        float gin = gib[(s*32 + m)*384 + 256 + j];
        float r = 1.f/(1.f + __expf(-ghs[s][j]));
        float z = 1.f/(1.f + __expf(-ghs[s][j+128]));
        float n = tanhf(gin + r*ghs[s][j+256]);
        hs[s][j] = (1.f - z)*n + z*hs[s][j];
      }
    }
    __syncthreads();
  }
  if (j < 128) {
    #pragma unroll
    for (int s = 0; s < 4; ++s)
      last[(run*NSEQ + grp*4 + s)*D_ + j] = hs[s][j];
  }
}

// =====================================================================
// visit-level gi precompute (small GEMM), 10 runs x 256 rows
// =====================================================================
__global__ __launch_bounds__(384) void k_vgi(
    const float* __restrict__ last, const float* __restrict__ xe,
    const float* __restrict__ wihTv, const float* __restrict__ vbih,
    float* __restrict__ vgi)
{
  int run = blockIdx.x >> 5;
  int rblk = blockIdx.x & 31;
  int j = threadIdx.x;
  int vidx = (run < 4) ? 0 : (run < 8) ? 1 : (run - 6);
  __shared__ float Xs[8][128];
  const float* X = (run < 8) ? (last + run*NSEQ*D_) : (xe + (run-8)*NSEQ*D_);
  for (int idx = j; idx < 1024; idx += 384) {
    int s = idx >> 7, k = idx & 127;
    Xs[s][k] = X[(rblk*8 + s)*D_ + k];
  }
  __syncthreads();
  float acc[8];
  float bias = vbih[vidx*384 + j];
  #pragma unroll
  for (int s = 0; s < 8; ++s) acc[s] = bias;
  const float* W = wihTv + vidx*49152 + j;
  #pragma unroll 4
  for (int k = 0; k < 128; ++k) {
    float wv = W[k*384];
    #pragma unroll
    for (int s = 0; s < 8; ++s) acc[s] += Xs[s][k] * wv;
  }
  #pragma unroll
  for (int s = 0; s < 8; ++s)
    vgi[(run*NSEQ + rblk*8 + s)*384 + j] = acc[s];
}

// =====================================================================
// visit-level GRU: 10 runs x 16 batch seqs, T=16. block = (run, b).
// =====================================================================
__global__ __launch_bounds__(384) void k_vgru(
    const float* __restrict__ vgi, const float* __restrict__ vWhh,
    const float* __restrict__ vbhh, float* __restrict__ vh)
{
  int run = blockIdx.x >> 4, b = blockIdx.x & 15;
  int j = threadIdx.x;
  int vidx = (run < 4) ? 0 : (run < 8) ? 1 : (run - 6);
  float w[128];
  const float4* wrow = (const float4*)(vWhh + (vidx*384 + j)*128);
  #pragma unroll
  for (int k4 = 0; k4 < 32; ++k4) {
    float4 tt = wrow[k4];
    w[4*k4] = tt.x; w[4*k4+1] = tt.y; w[4*k4+2] = tt.z; w[4*k4+3] = tt.w;
  }
  float bj = vbhh[vidx*384 + j];
  __shared__ __align__(16) float hsv[128];
  __shared__ float gh[384];
  if (j < 128) hsv[j] = 0.f;
  __syncthreads();
  const float* gib = vgi + (run*NSEQ + b*16)*384;
  #pragma unroll 1
  for (int v = 0; v < 16; ++v) {
    float acc = bj;
    if (j < 256) acc += gib[v*384 + j];
    const float4* h4 = (const float4*)hsv;
    #pragma unroll
    for (int k4 = 0; k4 < 32; ++k4) {
      float4 hv = h4[k4];
      acc += w[4*k4]*hv.x + w[4*k4+1]*hv.y + w[4*k4+2]*hv.z + w[4*k4+3]*hv.w;
    }
    gh[j] = acc;
    __syncthreads();
    if (j < 128) {
      float r = 1.f/(1.f + __expf(-gh[j]));
      float z = 1.f/(1.f + __expf(-gh[j+128]));
      float gin = gib[v*384 + 256 + j];
      float n = tanhf(gin + r*gh[j+256]);
      hsv[j] = (1.f - z)*n + z*hsv[j];
    }
    __syncthreads();
  }
  if (j < 128) vh[(run*16 + b)*D_ + j] = hsv[j];
}

// =====================================================================
// head: out[b][o] = bp[o] + sum_c relu(pe[b][c]) * Wp[o][c]
// =====================================================================
__global__ __launch_bounds__(256) void k_head(
    const float* __restrict__ vh, const float* __restrict__ Wp,
    const float* __restrict__ bp, float* __restrict__ out)
{
  int idx = blockIdx.x*256 + threadIdx.x;
  if (idx >= OUT_*16) return;
  int o = idx >> 4, b = idx & 15;
  const int a1[7] = {0,1,2,3,4,8,9};
  const int a2[7] = {-1,5,6,7,-1,-1,-1};
  float acc = bp[o];
  for (int s = 0; s < 7; ++s) {
    const float* v1 = vh + (a1[s]*16 + b)*D_;
    const float* v2 = (a2[s] >= 0) ? (vh + (a2[s]*16 + b)*D_) : nullptr;
    const float* w = Wp + o*896 + s*D_;
    #pragma unroll 4
    for (int d2 = 0; d2 < D_; ++d2) {
      float v = v1[d2] + (v2 ? v2[d2] : 0.f);
      v = v > 0.f ? v : 0.f;
      acc += v * w[d2];
    }
  }
  out[b*OUT_ + o] = acc;
}

// =====================================================================
extern "C" void kernel_launch(void* const* d_in, const int* in_sizes, int n_in,
                              void* d_out, int out_size, void* d_ws, size_t ws_size,
                              hipStream_t stream)
{
  (void)in_sizes; (void)n_in; (void)out_size; (void)ws_size;
  const int*   cc   = (const int*)  d_in[0];
  const int*   cp   = (const int*)  d_in[1];
  const int*   cd   = (const int*)  d_in[2];
  const int*   cli  = (const int*)  d_in[3];
  const int*   clv  = (const int*)  d_in[4];
  const int*   cii  = (const int*)  d_in[5];
  const int*   civ  = (const int*)  d_in[6];
  const float* wgt  = (const float*)d_in[7];
  const float* age  = (const float*)d_in[8];
  const float* ec   = (const float*)d_in[9];
  const float* ep   = (const float*)d_in[10];
  const float* ed   = (const float*)d_in[11];
  const float* eli  = (const float*)d_in[12];
  const float* elv  = (const float*)d_in[13];
  const float* eii  = (const float*)d_in[14];
  const float* eiv  = (const float*)d_in[15];
  const float* mWih = (const float*)d_in[16];
  const float* mWhh = (const float*)d_in[17];
  const float* mbih = (const float*)d_in[18];
  const float* mbhh = (const float*)d_in[19];
  const float* vWih = (const float*)d_in[20];
  const float* vWhh = (const float*)d_in[21];
  const float* vbih = (const float*)d_in[22];
  const float* vbhh = (const float*)d_in[23];
  const float* Wself= (const float*)d_in[24];
  const float* Wmsg = (const float*)d_in[25];
  const float* fwW  = (const float*)d_in[26];
  const float* fwB  = (const float*)d_in[27];
  const float* faW  = (const float*)d_in[28];
  const float* faB  = (const float*)d_in[29];
  const float* Wp   = (const float*)d_in[30];
  const float* bp   = (const float*)d_in[31];
  float* out = (float*)d_out;
  float* ws  = (float*)d_ws;

  float* vis   = ws + OFF_VIS;
  float* mon   = ws + OFF_MON;
  float* w12   = ws + OFF_W12;
  float* wihTm = ws + OFF_WIHTM;
  float* wihTv = ws + OFF_WIHTV;
  float* xe    = ws + OFF_XE;
  float* gnn   = ws + OFF_GNN;
  float* gi    = ws + OFF_GI;
  float* last  = ws + OFF_LAST;
  float* vgi   = ws + OFF_VGI;
  float* vh    = ws + OFF_VH;

  k_prep<<<2496, 256, 0, stream>>>(Wself, Wmsg, mWih, vWih, wgt, age,
                                   fwW, fwB, faW, faB, w12, wihTm, wihTv, xe);
  k_vis <<<768, 128, 0, stream>>>(cc, cp, cd, ec, ep, ed, vis);
  k_mon <<<16384, 128, 0, stream>>>(cli, clv, cii, civ, eli, elv, eii, eiv, mon);
  k_gnn <<<512, 256, 0, stream>>>(vis, mon, w12, gnn);
  k_gi  <<<1536, 256, 0, stream>>>(gnn, wihTm, mbih, gi);
  k_mgru<<<512, 384, 0, stream>>>(gi, mWhh, mbhh, last);
  k_vgi <<<320, 384, 0, stream>>>(last, xe, wihTv, vbih, vgi);
  k_vgru<<<160, 384, 0, stream>>>(vgi, vWhh, vbhh, vh);
  k_head<<<38, 256, 0, stream>>>(vh, Wp, bp, out);
}

// Round 4
// 669.171 us; speedup vs baseline: 1.4005x; 1.4005x over previous
//
#include <hip/hip_runtime.h>
#include <math.h>

#define B_   16
#define V_   16
#define C_   64
#define M_   32
#define CM_  16
#define D_   128
#define OUT_ 600
#define NSEQ 256      // B*V
#define NROW 8192     // B*V*M

// ---- workspace layout (floats) ----
constexpr int OFF_VIS   = 0;                              // [3][256][128]
constexpr int OFF_MON   = OFF_VIS   + 3*NSEQ*D_;          // [2][8192][128]
constexpr int OFF_W12   = OFF_MON   + 2*NROW*D_;          // [2][4][2][128][128]
constexpr int OFF_WIHTM = OFF_W12   + 2*4*2*D_*D_;        // [5][128][384]
constexpr int OFF_WIHTV = OFF_WIHTM + 5*D_*384;           // [4][128][384]
constexpr int OFF_XE    = OFF_WIHTV + 4*D_*384;           // [2][256][128]
constexpr int OFF_GNN   = OFF_XE    + 2*NSEQ*D_;          // [8][8192][128]
constexpr int OFF_GI    = OFF_GNN   + 8*NROW*D_;          // [8][8192][384]
constexpr int OFF_LAST  = OFF_GI    + 8*NROW*384;         // [8][256][128]
constexpr int OFF_VGI   = OFF_LAST  + 8*NSEQ*D_;          // [10][256][384]
constexpr int OFF_VH    = OFF_VGI   + 10*NSEQ*384;        // [10][16][128]

// =====================================================================
// prep: combined GNN weights, transposed Wih (monitor+visit), weight/age xe
// =====================================================================
__global__ __launch_bounds__(256) void k_prep(
    const float* __restrict__ Wself, const float* __restrict__ Wmsg,
    const float* __restrict__ mWih,  const float* __restrict__ vWih,
    const float* __restrict__ wgt,   const float* __restrict__ age,
    const float* __restrict__ fwW,   const float* __restrict__ fwB,
    const float* __restrict__ faW,   const float* __restrict__ faB,
    float* __restrict__ w12, float* __restrict__ wihTm,
    float* __restrict__ wihTv, float* __restrict__ xe)
{
  int bx = blockIdx.x, tid = threadIdx.x;
  if (bx < 512) {                       // W1 = Wself - Wmsg/3 ; W2 = Wmsg/3
    int lin = bx*256 + tid;             // < 131072
    int pt = lin >> 14, rem = lin & 16383;
    float wsv = Wself[pt*16384 + rem];
    float wmv = Wmsg [pt*16384 + rem];
    w12[(pt*2+0)*16384 + rem] = wsv - wmv*(1.f/3.f);
    w12[(pt*2+1)*16384 + rem] = wmv*(1.f/3.f);
  } else if (bx < 1472) {               // mgru Wih transpose [g][k][j]
    int lin = (bx-512)*256 + tid;       // < 245760
    int g = lin / 49152, rem = lin % 49152;
    int k = rem / 384, j = rem % 384;
    wihTm[lin] = mWih[g*49152 + j*128 + k];
  } else if (bx < 2240) {               // vgru Wih transpose
    int lin = (bx-1472)*256 + tid;      // < 196608
    int g = lin / 49152, rem = lin % 49152;
    int k = rem / 384, j = rem % 384;
    wihTv[lin] = vWih[g*49152 + j*128 + k];
  } else {                              // xe for weight / age
    int lin = (bx-2240)*256 + tid;      // < 65536
    int which = lin >> 15, rem = lin & 32767;
    int n = rem >> 7, d = rem & 127;
    float x  = which ? age[n] : wgt[n];
    float Wv = which ? faW[d] : fwW[d];
    float bb = which ? faB[d] : fwB[d];
    xe[lin] = (x != 0.0f) ? (x*Wv + bb) : 0.0f;
  }
}

// =====================================================================
// visit-event embedding sum pools: vis[type][bv][d]
// =====================================================================
__global__ __launch_bounds__(128) void k_vis(
    const int* __restrict__ cc, const int* __restrict__ cp, const int* __restrict__ cd,
    const float* __restrict__ ec, const float* __restrict__ ep, const float* __restrict__ ed,
    float* __restrict__ vis)
{
  int type = blockIdx.x >> 8;
  int bv   = blockIdx.x & 255;
  int d    = threadIdx.x;
  const int*   codes = (type==0) ? cc : (type==1) ? cp : cd;
  const float* emb   = (type==0) ? ec : (type==1) ? ep : ed;
  float acc = 0.f;
  for (int c = 0; c < C_; ++c) {
    int code = codes[bv*C_ + c];
    acc += emb[code*D_ + d];
  }
  vis[(type*NSEQ + bv)*D_ + d] = acc;
}

// =====================================================================
// monitor-event pools: mon[p][bvm][d] = sum_c ei[ci]*ev[cv]
// =====================================================================
__global__ __launch_bounds__(128) void k_mon(
    const int* __restrict__ cli, const int* __restrict__ clv,
    const int* __restrict__ cii, const int* __restrict__ civ,
    const float* __restrict__ eli, const float* __restrict__ elv,
    const float* __restrict__ eii, const float* __restrict__ eiv,
    float* __restrict__ mon)
{
  int p   = blockIdx.x >> 13;
  int bvm = blockIdx.x & 8191;
  int d   = threadIdx.x;
  const int* ci = p ? cii : cli;  const int* cv = p ? civ : clv;
  const float* ei = p ? eii : eli; const float* ev = p ? eiv : elv;
  float acc = 0.f;
  #pragma unroll
  for (int c = 0; c < CM_; ++c) {
    int iv = ci[bvm*CM_ + c];
    int vv = cv[bvm*CM_ + c];
    acc += ei[iv*D_ + d] * ev[vv*D_ + d];
  }
  mon[(p*NROW + bvm)*D_ + d] = acc;
}

// =====================================================================
// GNN: out[pt] = relu( feat@W1 + total@W2 )  as one K=256 GEMM
// =====================================================================
__global__ __launch_bounds__(256) void k_gnn(
    const float* __restrict__ vis, const float* __restrict__ mon,
    const float* __restrict__ w12, float* __restrict__ out)
{
  int pt   = blockIdx.x >> 6;
  int mblk = blockIdx.x & 63;
  int p = pt >> 2, t = pt & 3;
  int m0 = mblk * 128;
  int tid = threadIdx.x;
  __shared__ __align__(16) float Xs[32][132];
  __shared__ __align__(16) float Ws[32][132];
  float acc[8][8];
  #pragma unroll
  for (int i = 0; i < 8; ++i)
    #pragma unroll
    for (int jj = 0; jj < 8; ++jj) acc[i][jj] = 0.f;

  int tc = tid & 15, tr = tid >> 4;
  int kkS = tid & 31, rrS = tid >> 5;
  int cS  = tid & 127, kwS = tid >> 7;

  const float* monp = mon + p*NROW*D_;
  const float* visA = vis;
  const float* visB = vis + NSEQ*D_;
  const float* visC = vis + 2*NSEQ*D_;
  const float* featv = (t > 0) ? (vis + (t-1)*NSEQ*D_) : monp;

  for (int ks = 0; ks < 8; ++ks) {
    #pragma unroll
    for (int pass = 0; pass < 16; ++pass) {
      int r = rrS + pass*8;
      int row = m0 + r;
      int bv = row >> 5;
      int k = ks*32 + kkS;
      float v;
      if (k < 128) {
        v = (t == 0) ? monp[row*D_ + k] : featv[bv*D_ + k];
      } else {
        int k2 = k - 128;
        v = monp[row*D_ + k2] + visA[bv*D_ + k2] + visB[bv*D_ + k2] + visC[bv*D_ + k2];
      }
      Xs[kkS][r] = v;
    }
    #pragma unroll
    for (int pass = 0; pass < 16; ++pass) {
      int kk = kwS + pass*2;
      int k = ks*32 + kk;
      int which = (k >= 128) ? 1 : 0;
      Ws[kk][cS] = w12[((pt*2 + which)*128 + (k & 127))*128 + cS];
    }
    __syncthreads();
    #pragma unroll
    for (int kk = 0; kk < 32; ++kk) {
      float4 a0 = *(const float4*)&Xs[kk][tr*4];
      float4 a1 = *(const float4*)&Xs[kk][64 + tr*4];
      float4 b0 = *(const float4*)&Ws[kk][tc*4];
      float4 b1 = *(const float4*)&Ws[kk][64 + tc*4];
      float av[8] = {a0.x,a0.y,a0.z,a0.w,a1.x,a1.y,a1.z,a1.w};
      float bw[8] = {b0.x,b0.y,b0.z,b0.w,b1.x,b1.y,b1.z,b1.w};
      #pragma unroll
      for (int i = 0; i < 8; ++i)
        #pragma unroll
        for (int jj = 0; jj < 8; ++jj)
          acc[i][jj] += av[i]*bw[jj];
    }
    __syncthreads();
  }
  float* op = out + pt*NROW*D_;
  #pragma unroll
  for (int i = 0; i < 8; ++i) {
    int ri = (i < 4) ? (tr*4 + i) : (64 + tr*4 + i - 4);
    float4 v0 = make_float4(fmaxf(acc[i][0],0.f), fmaxf(acc[i][1],0.f),
                            fmaxf(acc[i][2],0.f), fmaxf(acc[i][3],0.f));
    float4 v1 = make_float4(fmaxf(acc[i][4],0.f), fmaxf(acc[i][5],0.f),
                            fmaxf(acc[i][6],0.f), fmaxf(acc[i][7],0.f));
    *(float4*)&op[(m0+ri)*D_ + tc*4] = v0;
    *(float4*)&op[(m0+ri)*D_ + 64 + tc*4] = v1;
  }
}

// =====================================================================
// gi precompute: gi[run][row][j] = gnn_out[run] @ WihT[g] + bih[g]
// =====================================================================
__global__ __launch_bounds__(256) void k_gi(
    const float* __restrict__ gnn, const float* __restrict__ wihTm,
    const float* __restrict__ mbih, float* __restrict__ gi)
{
  int bx = blockIdx.x;
  int run = bx / 192, rem = bx % 192;
  int mblk = rem / 3, nblk = rem % 3;
  int g = (run % 4 == 0) ? (run / 4) : (run % 4 + 1);
  int m0 = mblk * 128;
  int tid = threadIdx.x;
  __shared__ __align__(16) float Xs[32][132];
  __shared__ __align__(16) float Ws[32][132];
  float acc[8][8];
  #pragma unroll
  for (int i = 0; i < 8; ++i)
    #pragma unroll
    for (int jj = 0; jj < 8; ++jj) acc[i][jj] = 0.f;

  int tc = tid & 15, tr = tid >> 4;
  int kkS = tid & 31, rrS = tid >> 5;
  int cS  = tid & 127, kwS = tid >> 7;

  const float* X = gnn + run*NROW*D_;
  const float* W = wihTm + g*49152 + nblk*128;

  for (int ks = 0; ks < 4; ++ks) {
    #pragma unroll
    for (int pass = 0; pass < 16; ++pass) {
      int r = rrS + pass*8;
      Xs[kkS][r] = X[(m0 + r)*D_ + ks*32 + kkS];
    }
    #pragma unroll
    for (int pass = 0; pass < 16; ++pass) {
      int kk = kwS + pass*2;
      Ws[kk][cS] = W[(ks*32 + kk)*384 + cS];
    }
    __syncthreads();
    #pragma unroll
    for (int kk = 0; kk < 32; ++kk) {
      float4 a0 = *(const float4*)&Xs[kk][tr*4];
      float4 a1 = *(const float4*)&Xs[kk][64 + tr*4];
      float4 b0 = *(const float4*)&Ws[kk][tc*4];
      float4 b1 = *(const float4*)&Ws[kk][64 + tc*4];
      float av[8] = {a0.x,a0.y,a0.z,a0.w,a1.x,a1.y,a1.z,a1.w};
      float bw[8] = {b0.x,b0.y,b0.z,b0.w,b1.x,b1.y,b1.z,b1.w};
      #pragma unroll
      for (int i = 0; i < 8; ++i)
        #pragma unroll
        for (int jj = 0; jj < 8; ++jj)
          acc[i][jj] += av[i]*bw[jj];
    }
    __syncthreads();
  }
  const float* bb = mbih + g*384 + nblk*128;
  float4 bb0 = *(const float4*)&bb[tc*4];
  float4 bb1 = *(const float4*)&bb[64 + tc*4];
  #pragma unroll
  for (int i = 0; i < 8; ++i) {
    int ri = (i < 4) ? (tr*4 + i) : (64 + tr*4 + i - 4);
    float* rowp = gi + (run*NROW + m0 + ri)*384 + nblk*128;
    float4 v0 = make_float4(acc[i][0]+bb0.x, acc[i][1]+bb0.y, acc[i][2]+bb0.z, acc[i][3]+bb0.w);
    float4 v1 = make_float4(acc[i][4]+bb1.x, acc[i][5]+bb1.y, acc[i][6]+bb1.z, acc[i][7]+bb1.w);
    *(float4*)&rowp[tc*4] = v0;
    *(float4*)&rowp[64 + tc*4] = v1;
  }
}

// =====================================================================
// monitor-level GRU v3: 256 blocks x 768 threads (12 waves/CU resident).
// 8 seqs/block. Thread = (j4 in [0,96), kc in [0,8)); holds w[4][16]
// (64 VGPRs - no spill), computes 4 outputs over a 16-wide k-chunk;
// partials combined across 8 kc-lanes via shfl_xor.
// ghs carries the PURE matvec; gi and biases added once in the gate phase.
// =====================================================================
__global__ __launch_bounds__(768, 3) void k_mgru(
    const float* __restrict__ gi, const float* __restrict__ mWhh,
    const float* __restrict__ mbhh, float* __restrict__ last)
{
  int run = blockIdx.x >> 5, grp = blockIdx.x & 31;
  int tid = threadIdx.x;
  int j4 = tid >> 3, kc = tid & 7;
  int j0 = j4 * 4;
  int g = (run % 4 == 0) ? (run / 4) : (run % 4 + 1);

  float w[4][16];
  #pragma unroll
  for (int r = 0; r < 4; ++r) {
    const float4* wr = (const float4*)(mWhh + (g*384 + j0 + r)*128 + kc*16);
    #pragma unroll
    for (int q = 0; q < 4; ++q) {
      float4 t4 = wr[q];
      w[r][4*q] = t4.x; w[r][4*q+1] = t4.y; w[r][4*q+2] = t4.z; w[r][4*q+3] = t4.w;
    }
  }

  // gate-phase constants: item1 = tid, item2 = tid+768 (tid<256 only)
  int s_a = tid >> 7, j_a = tid & 127;
  int s_b = 6 + (tid >> 7), j_b = tid & 127;
  const float* bh = mbhh + g*384;
  float bh0a = bh[j_a], bh1a = bh[j_a+128], bh2a = bh[j_a+256];
  float bh0b = 0.f, bh1b = 0.f, bh2b = 0.f;
  if (tid < 256) { bh0b = bh[j_b]; bh1b = bh[j_b+128]; bh2b = bh[j_b+256]; }

  __shared__ __align__(16) float hs[8][128];
  __shared__ __align__(16) float ghs[8][384];
  for (int idx = tid; idx < 1024; idx += 768) hs[idx>>7][idx&127] = 0.f;
  __syncthreads();

  const float* gib = gi + (run*NROW + grp*256)*384;

  #pragma unroll 1
  for (int m = 0; m < 32; ++m) {
    // hoist gate-phase gi loads: in flight during the matvec below
    const float* ga = gib + (s_a*32 + m)*384;
    float gv0a = ga[j_a], gv1a = ga[j_a+128], gv2a = ga[j_a+256];
    float gv0b = 0.f, gv1b = 0.f, gv2b = 0.f;
    if (tid < 256) {
      const float* gb = gib + (s_b*32 + m)*384;
      gv0b = gb[j_b]; gv1b = gb[j_b+128]; gv2b = gb[j_b+256];
    }
    // ---- matvec: ghs[s][j] = sum_k Whh[j][k] * h[s][k] ----
    #pragma unroll 1
    for (int s = 0; s < 8; ++s) {
      const float4* h4 = (const float4*)(hs[s] + kc*16);
      float4 h0 = h4[0], h1 = h4[1], h2 = h4[2], h3 = h4[3];
      float hv[16] = {h0.x,h0.y,h0.z,h0.w, h1.x,h1.y,h1.z,h1.w,
                      h2.x,h2.y,h2.z,h2.w, h3.x,h3.y,h3.z,h3.w};
      float p0 = 0.f, p1 = 0.f, p2 = 0.f, p3 = 0.f;
      #pragma unroll
      for (int q = 0; q < 16; ++q) {
        p0 += w[0][q]*hv[q];
        p1 += w[1][q]*hv[q];
        p2 += w[2][q]*hv[q];
        p3 += w[3][q]*hv[q];
      }
      p0 += __shfl_xor(p0,1); p0 += __shfl_xor(p0,2); p0 += __shfl_xor(p0,4);
      p1 += __shfl_xor(p1,1); p1 += __shfl_xor(p1,2); p1 += __shfl_xor(p1,4);
      p2 += __shfl_xor(p2,1); p2 += __shfl_xor(p2,2); p2 += __shfl_xor(p2,4);
      p3 += __shfl_xor(p3,1); p3 += __shfl_xor(p3,2); p3 += __shfl_xor(p3,4);
      if (kc == 0) *(float4*)&ghs[s][j0] = make_float4(p0,p1,p2,p3);
    }
    __syncthreads();
    // ---- gates: 1024 items over 768 threads ----
    {
      float r = 1.f/(1.f + __expf(-(gv0a + bh0a + ghs[s_a][j_a])));
      float z = 1.f/(1.f + __expf(-(gv1a + bh1a + ghs[s_a][j_a+128])));
      float n = tanhf(gv2a + r*(bh2a + ghs[s_a][j_a+256]));
      hs[s_a][j_a] = (1.f - z)*n + z*hs[s_a][j_a];
      if (tid < 256) {
        float rb = 1.f/(1.f + __expf(-(gv0b + bh0b + ghs[s_b][j_b])));
        float zb = 1.f/(1.f + __expf(-(gv1b + bh1b + ghs[s_b][j_b+128])));
        float nb = tanhf(gv2b + rb*(bh2b + ghs[s_b][j_b+256]));
        hs[s_b][j_b] = (1.f - zb)*nb + zb*hs[s_b][j_b];
      }
    }
    __syncthreads();
  }
  for (int idx = tid; idx < 1024; idx += 768)
    last[(run*NSEQ + grp*8 + (idx>>7))*D_ + (idx&127)] = hs[idx>>7][idx&127];
}

// =====================================================================
// visit-level gi precompute (small GEMM), 10 runs x 256 rows
// =====================================================================
__global__ __launch_bounds__(384) void k_vgi(
    const float* __restrict__ last, const float* __restrict__ xe,
    const float* __restrict__ wihTv, const float* __restrict__ vbih,
    float* __restrict__ vgi)
{
  int run = blockIdx.x >> 5;
  int rblk = blockIdx.x & 31;
  int j = threadIdx.x;
  int vidx = (run < 4) ? 0 : (run < 8) ? 1 : (run - 6);
  __shared__ float Xs[8][128];
  const float* X = (run < 8) ? (last + run*NSEQ*D_) : (xe + (run-8)*NSEQ*D_);
  for (int idx = j; idx < 1024; idx += 384) {
    int s = idx >> 7, k = idx & 127;
    Xs[s][k] = X[(rblk*8 + s)*D_ + k];
  }
  __syncthreads();
  float acc[8];
  float bias = vbih[vidx*384 + j];
  #pragma unroll
  for (int s = 0; s < 8; ++s) acc[s] = bias;
  const float* W = wihTv + vidx*49152 + j;
  #pragma unroll 4
  for (int k = 0; k < 128; ++k) {
    float wv = W[k*384];
    #pragma unroll
    for (int s = 0; s < 8; ++s) acc[s] += Xs[s][k] * wv;
  }
  #pragma unroll
  for (int s = 0; s < 8; ++s)
    vgi[(run*NSEQ + rblk*8 + s)*384 + j] = acc[s];
}

// =====================================================================
// visit-level GRU v2.1: 160 blocks x 768 threads; pair-split (j, khalf),
// w[64] per thread (no spill). BUGFIX vs round 3: gi folded into gh only
// for the r/z rows (j<256) — n-row gi is added once in the gate phase.
// =====================================================================
__global__ __launch_bounds__(768) void k_vgru(
    const float* __restrict__ vgi, const float* __restrict__ vWhh,
    const float* __restrict__ vbhh, float* __restrict__ vh)
{
  int run = blockIdx.x >> 4, b = blockIdx.x & 15;
  int tid = threadIdx.x;
  int j = tid >> 1, kh = tid & 1;
  int vidx = (run < 4) ? 0 : (run < 8) ? 1 : (run - 6);
  float w[64];
  const float4* wrow = (const float4*)(vWhh + (vidx*384 + j)*128 + kh*64);
  #pragma unroll
  for (int k4 = 0; k4 < 16; ++k4) {
    float4 t4 = wrow[k4];
    w[4*k4] = t4.x; w[4*k4+1] = t4.y; w[4*k4+2] = t4.z; w[4*k4+3] = t4.w;
  }
  float bj = vbhh[vidx*384 + j];
  __shared__ __align__(16) float hsv[128];
  __shared__ float gh[384];
  if (tid < 128) hsv[tid] = 0.f;
  __syncthreads();
  const float* gib = vgi + (run*NSEQ + b*16)*384;
  #pragma unroll 1
  for (int v = 0; v < 16; ++v) {
    const float4* h4 = (const float4*)(hsv + kh*64);
    float p0 = 0.f, p1 = 0.f;
    #pragma unroll
    for (int k4 = 0; k4 < 8; ++k4) {
      float4 u0 = h4[k4], u1 = h4[k4+8];
      p0 += w[4*k4   ]*u0.x + w[4*k4+1 ]*u0.y + w[4*k4+2 ]*u0.z + w[4*k4+3 ]*u0.w;
      p1 += w[4*k4+32]*u1.x + w[4*k4+33]*u1.y + w[4*k4+34]*u1.z + w[4*k4+35]*u1.w;
    }
    float part = p0 + p1;
    part += __shfl_xor(part, 1);
    if (kh == 0) gh[j] = bj + ((j < 256) ? gib[v*384 + j] : 0.f) + part;
    __syncthreads();
    if (tid < 128) {
      float r = 1.f/(1.f + __expf(-gh[tid]));
      float z = 1.f/(1.f + __expf(-gh[tid+128]));
      float gin = gib[v*384 + 256 + tid];
      float n = tanhf(gin + r*gh[tid+256]);
      hsv[tid] = (1.f - z)*n + z*hsv[tid];
    }
    __syncthreads();
  }
  if (tid < 128) vh[(run*16 + b)*D_ + tid] = hsv[tid];
}

// =====================================================================
// head: out[b][o] = bp[o] + sum_c relu(pe[b][c]) * Wp[o][c]
// =====================================================================
__global__ __launch_bounds__(256) void k_head(
    const float* __restrict__ vh, const float* __restrict__ Wp,
    const float* __restrict__ bp, float* __restrict__ out)
{
  int idx = blockIdx.x*256 + threadIdx.x;
  if (idx >= OUT_*16) return;
  int o = idx >> 4, b = idx & 15;
  const int a1[7] = {0,1,2,3,4,8,9};
  const int a2[7] = {-1,5,6,7,-1,-1,-1};
  float acc = bp[o];
  for (int s = 0; s < 7; ++s) {
    const float* v1 = vh + (a1[s]*16 + b)*D_;
    const float* v2 = (a2[s] >= 0) ? (vh + (a2[s]*16 + b)*D_) : nullptr;
    const float* w = Wp + o*896 + s*D_;
    #pragma unroll 4
    for (int d2 = 0; d2 < D_; ++d2) {
      float v = v1[d2] + (v2 ? v2[d2] : 0.f);
      v = v > 0.f ? v : 0.f;
      acc += v * w[d2];
    }
  }
  out[b*OUT_ + o] = acc;
}

// =====================================================================
extern "C" void kernel_launch(void* const* d_in, const int* in_sizes, int n_in,
                              void* d_out, int out_size, void* d_ws, size_t ws_size,
                              hipStream_t stream)
{
  (void)in_sizes; (void)n_in; (void)out_size; (void)ws_size;
  const int*   cc   = (const int*)  d_in[0];
  const int*   cp   = (const int*)  d_in[1];
  const int*   cd   = (const int*)  d_in[2];
  const int*   cli  = (const int*)  d_in[3];
  const int*   clv  = (const int*)  d_in[4];
  const int*   cii  = (const int*)  d_in[5];
  const int*   civ  = (const int*)  d_in[6];
  const float* wgt  = (const float*)d_in[7];
  const float* age  = (const float*)d_in[8];
  const float* ec   = (const float*)d_in[9];
  const float* ep   = (const float*)d_in[10];
  const float* ed   = (const float*)d_in[11];
  const float* eli  = (const float*)d_in[12];
  const float* elv  = (const float*)d_in[13];
  const float* eii  = (const float*)d_in[14];
  const float* eiv  = (const float*)d_in[15];
  const float* mWih = (const float*)d_in[16];
  const float* mWhh = (const float*)d_in[17];
  const float* mbih = (const float*)d_in[18];
  const float* mbhh = (const float*)d_in[19];
  const float* vWih = (const float*)d_in[20];
  const float* vWhh = (const float*)d_in[21];
  const float* vbih = (const float*)d_in[22];
  const float* vbhh = (const float*)d_in[23];
  const float* Wself= (const float*)d_in[24];
  const float* Wmsg = (const float*)d_in[25];
  const float* fwW  = (const float*)d_in[26];
  const float* fwB  = (const float*)d_in[27];
  const float* faW  = (const float*)d_in[28];
  const float* faB  = (const float*)d_in[29];
  const float* Wp   = (const float*)d_in[30];
  const float* bp   = (const float*)d_in[31];
  float* out = (float*)d_out;
  float* ws  = (float*)d_ws;

  float* vis   = ws + OFF_VIS;
  float* mon   = ws + OFF_MON;
  float* w12   = ws + OFF_W12;
  float* wihTm = ws + OFF_WIHTM;
  float* wihTv = ws + OFF_WIHTV;
  float* xe    = ws + OFF_XE;
  float* gnn   = ws + OFF_GNN;
  float* gi    = ws + OFF_GI;
  float* last  = ws + OFF_LAST;
  float* vgi   = ws + OFF_VGI;
  float* vh    = ws + OFF_VH;

  k_prep<<<2496, 256, 0, stream>>>(Wself, Wmsg, mWih, vWih, wgt, age,
                                   fwW, fwB, faW, faB, w12, wihTm, wihTv, xe);
  k_vis <<<768, 128, 0, stream>>>(cc, cp, cd, ec, ep, ed, vis);
  k_mon <<<16384, 128, 0, stream>>>(cli, clv, cii, civ, eli, elv, eii, eiv, mon);
  k_gnn <<<512, 256, 0, stream>>>(vis, mon, w12, gnn);
  k_gi  <<<1536, 256, 0, stream>>>(gnn, wihTm, mbih, gi);
  k_mgru<<<256, 768, 0, stream>>>(gi, mWhh, mbhh, last);
  k_vgi <<<320, 384, 0, stream>>>(last, xe, wihTv, vbih, vgi);
  k_vgru<<<160, 768, 0, stream>>>(vgi, vWhh, vbhh, vh);
  k_head<<<38, 256, 0, stream>>>(vh, Wp, bp, out);
}

// Round 5
// 562.577 us; speedup vs baseline: 1.6658x; 1.1895x over previous
//
#include <hip/hip_runtime.h>
#include <math.h>

#define B_   16
#define V_   16
#define C_   64
#define M_   32
#define CM_  16
#define D_   128
#define OUT_ 600
#define NSEQ 256      // B*V
#define NROW 8192     // B*V*M

typedef __attribute__((ext_vector_type(8))) short bf16x8;
typedef __attribute__((ext_vector_type(4))) float f32x4;

__device__ __forceinline__ unsigned short f2bf(float x) {
  union { float f; unsigned u; } v; v.f = x;
  unsigned r = v.u + 0x7fff + ((v.u >> 16) & 1);   // RNE
  return (unsigned short)(r >> 16);
}

// ---- workspace layout (floats) ----
constexpr int OFF_VIS   = 0;                              // [3][256][128]
constexpr int OFF_MON   = OFF_VIS   + 3*NSEQ*D_;          // [2][8192][128]
constexpr int OFF_W12   = OFF_MON   + 2*NROW*D_;          // [2][4][2][128][128]
constexpr int OFF_WIHTM = OFF_W12   + 2*4*2*D_*D_;        // [5][128][384]
constexpr int OFF_WIHTV = OFF_WIHTM + 5*D_*384;           // [4][128][384]
constexpr int OFF_XE    = OFF_WIHTV + 4*D_*384;           // [2][256][128]
constexpr int OFF_GNN   = OFF_XE    + 2*NSEQ*D_;          // [8][8192][128]
constexpr int OFF_GI    = OFF_GNN   + 8*NROW*D_;          // [8][8192][384]
constexpr int OFF_LAST  = OFF_GI    + 8*NROW*384;         // [8][256][128]
constexpr int OFF_VGI   = OFF_LAST  + 8*NSEQ*D_;          // [10][256][384]
constexpr int OFF_VH    = OFF_VGI   + 10*NSEQ*384;        // [10][16][128]

// =====================================================================
// prep: combined GNN weights, transposed Wih (monitor+visit), weight/age xe
// =====================================================================
__global__ __launch_bounds__(256) void k_prep(
    const float* __restrict__ Wself, const float* __restrict__ Wmsg,
    const float* __restrict__ mWih,  const float* __restrict__ vWih,
    const float* __restrict__ wgt,   const float* __restrict__ age,
    const float* __restrict__ fwW,   const float* __restrict__ fwB,
    const float* __restrict__ faW,   const float* __restrict__ faB,
    float* __restrict__ w12, float* __restrict__ wihTm,
    float* __restrict__ wihTv, float* __restrict__ xe)
{
  int bx = blockIdx.x, tid = threadIdx.x;
  if (bx < 512) {                       // W1 = Wself - Wmsg/3 ; W2 = Wmsg/3
    int lin = bx*256 + tid;             // < 131072
    int pt = lin >> 14, rem = lin & 16383;
    float wsv = Wself[pt*16384 + rem];
    float wmv = Wmsg [pt*16384 + rem];
    w12[(pt*2+0)*16384 + rem] = wsv - wmv*(1.f/3.f);
    w12[(pt*2+1)*16384 + rem] = wmv*(1.f/3.f);
  } else if (bx < 1472) {               // mgru Wih transpose [g][k][j]
    int lin = (bx-512)*256 + tid;       // < 245760
    int g = lin / 49152, rem = lin % 49152;
    int k = rem / 384, j = rem % 384;
    wihTm[lin] = mWih[g*49152 + j*128 + k];
  } else if (bx < 2240) {               // vgru Wih transpose
    int lin = (bx-1472)*256 + tid;      // < 196608
    int g = lin / 49152, rem = lin % 49152;
    int k = rem / 384, j = rem % 384;
    wihTv[lin] = vWih[g*49152 + j*128 + k];
  } else {                              // xe for weight / age
    int lin = (bx-2240)*256 + tid;      // < 65536
    int which = lin >> 15, rem = lin & 32767;
    int n = rem >> 7, d = rem & 127;
    float x  = which ? age[n] : wgt[n];
    float Wv = which ? faW[d] : fwW[d];
    float bb = which ? faB[d] : fwB[d];
    xe[lin] = (x != 0.0f) ? (x*Wv + bb) : 0.0f;
  }
}

// =====================================================================
// visit-event embedding sum pools: vis[type][bv][d]
// =====================================================================
__global__ __launch_bounds__(128) void k_vis(
    const int* __restrict__ cc, const int* __restrict__ cp, const int* __restrict__ cd,
    const float* __restrict__ ec, const float* __restrict__ ep, const float* __restrict__ ed,
    float* __restrict__ vis)
{
  int type = blockIdx.x >> 8;
  int bv   = blockIdx.x & 255;
  int d    = threadIdx.x;
  const int*   codes = (type==0) ? cc : (type==1) ? cp : cd;
  const float* emb   = (type==0) ? ec : (type==1) ? ep : ed;
  float acc = 0.f;
  for (int c = 0; c < C_; ++c) {
    int code = codes[bv*C_ + c];
    acc += emb[code*D_ + d];
  }
  vis[(type*NSEQ + bv)*D_ + d] = acc;
}

// =====================================================================
// monitor-event pools: mon[p][bvm][d] = sum_c ei[ci]*ev[cv]
// =====================================================================
__global__ __launch_bounds__(128) void k_mon(
    const int* __restrict__ cli, const int* __restrict__ clv,
    const int* __restrict__ cii, const int* __restrict__ civ,
    const float* __restrict__ eli, const float* __restrict__ elv,
    const float* __restrict__ eii, const float* __restrict__ eiv,
    float* __restrict__ mon)
{
  int p   = blockIdx.x >> 13;
  int bvm = blockIdx.x & 8191;
  int d   = threadIdx.x;
  const int* ci = p ? cii : cli;  const int* cv = p ? civ : clv;
  const float* ei = p ? eii : eli; const float* ev = p ? eiv : elv;
  float acc = 0.f;
  #pragma unroll
  for (int c = 0; c < CM_; ++c) {
    int iv = ci[bvm*CM_ + c];
    int vv = cv[bvm*CM_ + c];
    acc += ei[iv*D_ + d] * ev[vv*D_ + d];
  }
  mon[(p*NROW + bvm)*D_ + d] = acc;
}

// =====================================================================
// GNN: out[pt] = relu( feat@W1 + total@W2 )  as one K=256 GEMM
// =====================================================================
__global__ __launch_bounds__(256) void k_gnn(
    const float* __restrict__ vis, const float* __restrict__ mon,
    const float* __restrict__ w12, float* __restrict__ out)
{
  int pt   = blockIdx.x >> 6;
  int mblk = blockIdx.x & 63;
  int p = pt >> 2, t = pt & 3;
  int m0 = mblk * 128;
  int tid = threadIdx.x;
  __shared__ __align__(16) float Xs[32][132];
  __shared__ __align__(16) float Ws[32][132];
  float acc[8][8];
  #pragma unroll
  for (int i = 0; i < 8; ++i)
    #pragma unroll
    for (int jj = 0; jj < 8; ++jj) acc[i][jj] = 0.f;

  int tc = tid & 15, tr = tid >> 4;
  int kkS = tid & 31, rrS = tid >> 5;
  int cS  = tid & 127, kwS = tid >> 7;

  const float* monp = mon + p*NROW*D_;
  const float* visA = vis;
  const float* visB = vis + NSEQ*D_;
  const float* visC = vis + 2*NSEQ*D_;
  const float* featv = (t > 0) ? (vis + (t-1)*NSEQ*D_) : monp;

  for (int ks = 0; ks < 8; ++ks) {
    #pragma unroll
    for (int pass = 0; pass < 16; ++pass) {
      int r = rrS + pass*8;
      int row = m0 + r;
      int bv = row >> 5;
      int k = ks*32 + kkS;
      float v;
      if (k < 128) {
        v = (t == 0) ? monp[row*D_ + k] : featv[bv*D_ + k];
      } else {
        int k2 = k - 128;
        v = monp[row*D_ + k2] + visA[bv*D_ + k2] + visB[bv*D_ + k2] + visC[bv*D_ + k2];
      }
      Xs[kkS][r] = v;
    }
    #pragma unroll
    for (int pass = 0; pass < 16; ++pass) {
      int kk = kwS + pass*2;
      int k = ks*32 + kk;
      int which = (k >= 128) ? 1 : 0;
      Ws[kk][cS] = w12[((pt*2 + which)*128 + (k & 127))*128 + cS];
    }
    __syncthreads();
    #pragma unroll
    for (int kk = 0; kk < 32; ++kk) {
      float4 a0 = *(const float4*)&Xs[kk][tr*4];
      float4 a1 = *(const float4*)&Xs[kk][64 + tr*4];
      float4 b0 = *(const float4*)&Ws[kk][tc*4];
      float4 b1 = *(const float4*)&Ws[kk][64 + tc*4];
      float av[8] = {a0.x,a0.y,a0.z,a0.w,a1.x,a1.y,a1.z,a1.w};
      float bw[8] = {b0.x,b0.y,b0.z,b0.w,b1.x,b1.y,b1.z,b1.w};
      #pragma unroll
      for (int i = 0; i < 8; ++i)
        #pragma unroll
        for (int jj = 0; jj < 8; ++jj)
          acc[i][jj] += av[i]*bw[jj];
    }
    __syncthreads();
  }
  float* op = out + pt*NROW*D_;
  #pragma unroll
  for (int i = 0; i < 8; ++i) {
    int ri = (i < 4) ? (tr*4 + i) : (64 + tr*4 + i - 4);
    float4 v0 = make_float4(fmaxf(acc[i][0],0.f), fmaxf(acc[i][1],0.f),
                            fmaxf(acc[i][2],0.f), fmaxf(acc[i][3],0.f));
    float4 v1 = make_float4(fmaxf(acc[i][4],0.f), fmaxf(acc[i][5],0.f),
                            fmaxf(acc[i][6],0.f), fmaxf(acc[i][7],0.f));
    *(float4*)&op[(m0+ri)*D_ + tc*4] = v0;
    *(float4*)&op[(m0+ri)*D_ + 64 + tc*4] = v1;
  }
}

// =====================================================================
// gi precompute: gi[run][row][j] = gnn_out[run] @ WihT[g] + bih[g]
// =====================================================================
__global__ __launch_bounds__(256) void k_gi(
    const float* __restrict__ gnn, const float* __restrict__ wihTm,
    const float* __restrict__ mbih, float* __restrict__ gi)
{
  int bx = blockIdx.x;
  int run = bx / 192, rem = bx % 192;
  int mblk = rem / 3, nblk = rem % 3;
  int g = (run % 4 == 0) ? (run / 4) : (run % 4 + 1);
  int m0 = mblk * 128;
  int tid = threadIdx.x;
  __shared__ __align__(16) float Xs[32][132];
  __shared__ __align__(16) float Ws[32][132];
  float acc[8][8];
  #pragma unroll
  for (int i = 0; i < 8; ++i)
    #pragma unroll
    for (int jj = 0; jj < 8; ++jj) acc[i][jj] = 0.f;

  int tc = tid & 15, tr = tid >> 4;
  int kkS = tid & 31, rrS = tid >> 5;
  int cS  = tid & 127, kwS = tid >> 7;

  const float* X = gnn + run*NROW*D_;
  const float* W = wihTm + g*49152 + nblk*128;

  for (int ks = 0; ks < 4; ++ks) {
    #pragma unroll
    for (int pass = 0; pass < 16; ++pass) {
      int r = rrS + pass*8;
      Xs[kkS][r] = X[(m0 + r)*D_ + ks*32 + kkS];
    }
    #pragma unroll
    for (int pass = 0; pass < 16; ++pass) {
      int kk = kwS + pass*2;
      Ws[kk][cS] = W[(ks*32 + kk)*384 + cS];
    }
    __syncthreads();
    #pragma unroll
    for (int kk = 0; kk < 32; ++kk) {
      float4 a0 = *(const float4*)&Xs[kk][tr*4];
      float4 a1 = *(const float4*)&Xs[kk][64 + tr*4];
      float4 b0 = *(const float4*)&Ws[kk][tc*4];
      float4 b1 = *(const float4*)&Ws[kk][64 + tc*4];
      float av[8] = {a0.x,a0.y,a0.z,a0.w,a1.x,a1.y,a1.z,a1.w};
      float bw[8] = {b0.x,b0.y,b0.z,b0.w,b1.x,b1.y,b1.z,b1.w};
      #pragma unroll
      for (int i = 0; i < 8; ++i)
        #pragma unroll
        for (int jj = 0; jj < 8; ++jj)
          acc[i][jj] += av[i]*bw[jj];
    }
    __syncthreads();
  }
  const float* bb = mbih + g*384 + nblk*128;
  float4 bb0 = *(const float4*)&bb[tc*4];
  float4 bb1 = *(const float4*)&bb[64 + tc*4];
  #pragma unroll
  for (int i = 0; i < 8; ++i) {
    int ri = (i < 4) ? (tr*4 + i) : (64 + tr*4 + i - 4);
    float* rowp = gi + (run*NROW + m0 + ri)*384 + nblk*128;
    float4 v0 = make_float4(acc[i][0]+bb0.x, acc[i][1]+bb0.y, acc[i][2]+bb0.z, acc[i][3]+bb0.w);
    float4 v1 = make_float4(acc[i][4]+bb1.x, acc[i][5]+bb1.y, acc[i][6]+bb1.z, acc[i][7]+bb1.w);
    *(float4*)&rowp[tc*4] = v0;
    *(float4*)&rowp[64 + tc*4] = v1;
  }
}

// =====================================================================
// monitor-level GRU v4 (MFMA): 256 blocks (run x 8-seq grp) x 256 thr.
// Per step: gh[8][384] = h_bf16[8][128] @ WhhT via mfma_f32_16x16x32_bf16.
// Wave w owns N-tiles {w,w+4}(r), {w+8,w+12}(z), {w+16,w+20}(n) — B-frags
// (Whh bf16) preloaded once in 96 VGPRs. h kept bf16 in double-buffered
// LDS [kt][row][40] (16B-aligned, bank-staggered); gates computed fully
// in registers from the C/D layout (col=lane&15, row=(lane>>4)*4+reg).
// gi prefetched one step ahead. h master fp32 in registers. 1 barrier/step.
// =====================================================================
__global__ __launch_bounds__(256, 1) void k_mgru(
    const float* __restrict__ gi, const float* __restrict__ mWhh,
    const float* __restrict__ mbhh, float* __restrict__ last)
{
  const int run = blockIdx.x >> 5, grp = blockIdx.x & 31;
  const int g = (run % 4 == 0) ? (run / 4) : (run % 4 + 1);
  const int tid = threadIdx.x;
  const int w = tid >> 6;            // wave 0..3
  const int lane = tid & 63;
  const int c = lane & 15, q = lane >> 4;

  __shared__ short hb[2][4][16][40];  // [buf][kt][row][32 + 8 pad] bf16

  for (int idx = tid; idx < 2*4*16*40; idx += 256)
    ((short*)hb)[idx] = 0;

  // ---- B fragments: Whh[j=n][k], lane holds k = kt*32 + q*8 + i, n = tile*16 + c
  bf16x8 bfrag[2][3][4];
  #pragma unroll
  for (int jj = 0; jj < 2; ++jj)
    #pragma unroll
    for (int gate = 0; gate < 3; ++gate) {
      int n = (w + jj*4 + gate*8)*16 + c;
      const float* wp = mWhh + (g*384 + n)*128 + q*8;
      #pragma unroll
      for (int kt = 0; kt < 4; ++kt) {
        float4 lo = *(const float4*)(wp + kt*32);
        float4 hi = *(const float4*)(wp + kt*32 + 4);
        bf16x8 t;
        t[0]=(short)f2bf(lo.x); t[1]=(short)f2bf(lo.y); t[2]=(short)f2bf(lo.z); t[3]=(short)f2bf(lo.w);
        t[4]=(short)f2bf(hi.x); t[5]=(short)f2bf(hi.y); t[6]=(short)f2bf(hi.z); t[7]=(short)f2bf(hi.w);
        bfrag[jj][gate][kt] = t;
      }
    }

  const int j0 = w*16 + c;            // jj=0 hidden index
  const int j1 = (w+4)*16 + c;        // jj=1 hidden index
  const float* bh = mbhh + g*384;
  float bh_[2][3];
  bh_[0][0]=bh[j0]; bh_[0][1]=bh[j0+128]; bh_[0][2]=bh[j0+256];
  bh_[1][0]=bh[j1]; bh_[1][1]=bh[j1+128]; bh_[1][2]=bh[j1+256];

  float hf[2][4] = {{0.f,0.f,0.f,0.f},{0.f,0.f,0.f,0.f}};
  const float* gib = gi + (run*NROW + grp*8*32)*384;
  const bool act = (lane < 32);       // rows 0..7 live in lanes 0..31

  // prefetch gi for m=0
  float gc[2][3][4];
  if (act) {
    #pragma unroll
    for (int jj = 0; jj < 2; ++jj) {
      int j = jj ? j1 : j0;
      #pragma unroll
      for (int gate = 0; gate < 3; ++gate)
        #pragma unroll
        for (int reg = 0; reg < 4; ++reg)
          gc[jj][gate][reg] = gib[((q*4+reg)*32 + 0)*384 + gate*128 + j];
    }
  }
  __syncthreads();

  int cur = 0;
  #pragma unroll 1
  for (int m = 0; m < 32; ++m) {
    // A-frags: A[row=c][k = kt*32 + q*8 + i]
    bf16x8 a[4];
    #pragma unroll
    for (int kt = 0; kt < 4; ++kt)
      a[kt] = *(const bf16x8*)&hb[cur][kt][c][q*8];

    f32x4 acc[2][3];
    #pragma unroll
    for (int jj = 0; jj < 2; ++jj)
      #pragma unroll
      for (int gate = 0; gate < 3; ++gate) {
        f32x4 t = {0.f,0.f,0.f,0.f};
        #pragma unroll
        for (int kt = 0; kt < 4; ++kt)
          t = __builtin_amdgcn_mfma_f32_16x16x32_bf16(a[kt], bfrag[jj][gate][kt], t, 0, 0, 0);
        acc[jj][gate] = t;
      }

    // prefetch next step's gi (hidden behind gate math)
    float gn[2][3][4];
    if (act && m < 31) {
      #pragma unroll
      for (int jj = 0; jj < 2; ++jj) {
        int j = jj ? j1 : j0;
        #pragma unroll
        for (int gate = 0; gate < 3; ++gate)
          #pragma unroll
          for (int reg = 0; reg < 4; ++reg)
            gn[jj][gate][reg] = gib[((q*4+reg)*32 + (m+1))*384 + gate*128 + j];
      }
    }

    const int nxt = cur ^ 1;
    if (act) {
      #pragma unroll
      for (int jj = 0; jj < 2; ++jj) {
        int j = jj ? j1 : j0;
        int kt = j >> 5, kk = j & 31;
        #pragma unroll
        for (int reg = 0; reg < 4; ++reg) {
          int row = q*4 + reg;
          float rp = acc[jj][0][reg] + bh_[jj][0] + gc[jj][0][reg];
          float zp = acc[jj][1][reg] + bh_[jj][1] + gc[jj][1][reg];
          float hg = acc[jj][2][reg] + bh_[jj][2];
          float rr = 1.f/(1.f + __expf(-rp));
          float zz = 1.f/(1.f + __expf(-zp));
          float nn = tanhf(gc[jj][2][reg] + rr*hg);
          float hnew = (1.f - zz)*nn + zz*hf[jj][reg];
          hf[jj][reg] = hnew;
          hb[nxt][kt][row][kk] = (short)f2bf(hnew);
        }
      }
      if (m < 31) {
        #pragma unroll
        for (int jj = 0; jj < 2; ++jj)
          #pragma unroll
          for (int gate = 0; gate < 3; ++gate)
            #pragma unroll
            for (int reg = 0; reg < 4; ++reg)
              gc[jj][gate][reg] = gn[jj][gate][reg];
      }
    }
    __syncthreads();
    cur = nxt;
  }

  if (act) {
    #pragma unroll
    for (int jj = 0; jj < 2; ++jj) {
      int j = jj ? j1 : j0;
      #pragma unroll
      for (int reg = 0; reg < 4; ++reg)
        last[(run*NSEQ + grp*8 + q*4 + reg)*D_ + j] = hf[jj][reg];
    }
  }
}

// =====================================================================
// visit-level gi precompute (small GEMM), 10 runs x 256 rows
// =====================================================================
__global__ __launch_bounds__(384) void k_vgi(
    const float* __restrict__ last, const float* __restrict__ xe,
    const float* __restrict__ wihTv, const float* __restrict__ vbih,
    float* __restrict__ vgi)
{
  int run = blockIdx.x >> 5;
  int rblk = blockIdx.x & 31;
  int j = threadIdx.x;
  int vidx = (run < 4) ? 0 : (run < 8) ? 1 : (run - 6);
  __shared__ float Xs[8][128];
  const float* X = (run < 8) ? (last + run*NSEQ*D_) : (xe + (run-8)*NSEQ*D_);
  for (int idx = j; idx < 1024; idx += 384) {
    int s = idx >> 7, k = idx & 127;
    Xs[s][k] = X[(rblk*8 + s)*D_ + k];
  }
  __syncthreads();
  float acc[8];
  float bias = vbih[vidx*384 + j];
  #pragma unroll
  for (int s = 0; s < 8; ++s) acc[s] = bias;
  const float* W = wihTv + vidx*49152 + j;
  #pragma unroll 4
  for (int k = 0; k < 128; ++k) {
    float wv = W[k*384];
    #pragma unroll
    for (int s = 0; s < 8; ++s) acc[s] += Xs[s][k] * wv;
  }
  #pragma unroll
  for (int s = 0; s < 8; ++s)
    vgi[(run*NSEQ + rblk*8 + s)*384 + j] = acc[s];
}

// =====================================================================
// visit-level GRU v2.1: 160 blocks x 768 threads; pair-split (j, khalf),
// w[64] per thread (no spill); gi folded into gh only for r/z rows.
// =====================================================================
__global__ __launch_bounds__(768) void k_vgru(
    const float* __restrict__ vgi, const float* __restrict__ vWhh,
    const float* __restrict__ vbhh, float* __restrict__ vh)
{
  int run = blockIdx.x >> 4, b = blockIdx.x & 15;
  int tid = threadIdx.x;
  int j = tid >> 1, kh = tid & 1;
  int vidx = (run < 4) ? 0 : (run < 8) ? 1 : (run - 6);
  float w[64];
  const float4* wrow = (const float4*)(vWhh + (vidx*384 + j)*128 + kh*64);
  #pragma unroll
  for (int k4 = 0; k4 < 16; ++k4) {
    float4 t4 = wrow[k4];
    w[4*k4] = t4.x; w[4*k4+1] = t4.y; w[4*k4+2] = t4.z; w[4*k4+3] = t4.w;
  }
  float bj = vbhh[vidx*384 + j];
  __shared__ __align__(16) float hsv[128];
  __shared__ float gh[384];
  if (tid < 128) hsv[tid] = 0.f;
  __syncthreads();
  const float* gib = vgi + (run*NSEQ + b*16)*384;
  #pragma unroll 1
  for (int v = 0; v < 16; ++v) {
    const float4* h4 = (const float4*)(hsv + kh*64);
    float p0 = 0.f, p1 = 0.f;
    #pragma unroll
    for (int k4 = 0; k4 < 8; ++k4) {
      float4 u0 = h4[k4], u1 = h4[k4+8];
      p0 += w[4*k4   ]*u0.x + w[4*k4+1 ]*u0.y + w[4*k4+2 ]*u0.z + w[4*k4+3 ]*u0.w;
      p1 += w[4*k4+32]*u1.x + w[4*k4+33]*u1.y + w[4*k4+34]*u1.z + w[4*k4+35]*u1.w;
    }
    float part = p0 + p1;
    part += __shfl_xor(part, 1);
    if (kh == 0) gh[j] = bj + ((j < 256) ? gib[v*384 + j] : 0.f) + part;
    __syncthreads();
    if (tid < 128) {
      float r = 1.f/(1.f + __expf(-gh[tid]));
      float z = 1.f/(1.f + __expf(-gh[tid+128]));
      float gin = gib[v*384 + 256 + tid];
      float n = tanhf(gin + r*gh[tid+256]);
      hsv[tid] = (1.f - z)*n + z*hsv[tid];
    }
    __syncthreads();
  }
  if (tid < 128) vh[(run*16 + b)*D_ + tid] = hsv[tid];
}

// =====================================================================
// head: out[b][o] = bp[o] + sum_c relu(pe[b][c]) * Wp[o][c]
// =====================================================================
__global__ __launch_bounds__(256) void k_head(
    const float* __restrict__ vh, const float* __restrict__ Wp,
    const float* __restrict__ bp, float* __restrict__ out)
{
  int idx = blockIdx.x*256 + threadIdx.x;
  if (idx >= OUT_*16) return;
  int o = idx >> 4, b = idx & 15;
  const int a1[7] = {0,1,2,3,4,8,9};
  const int a2[7] = {-1,5,6,7,-1,-1,-1};
  float acc = bp[o];
  for (int s = 0; s < 7; ++s) {
    const float* v1 = vh + (a1[s]*16 + b)*D_;
    const float* v2 = (a2[s] >= 0) ? (vh + (a2[s]*16 + b)*D_) : nullptr;
    const float* w = Wp + o*896 + s*D_;
    #pragma unroll 4
    for (int d2 = 0; d2 < D_; ++d2) {
      float v = v1[d2] + (v2 ? v2[d2] : 0.f);
      v = v > 0.f ? v : 0.f;
      acc += v * w[d2];
    }
  }
  out[b*OUT_ + o] = acc;
}

// =====================================================================
extern "C" void kernel_launch(void* const* d_in, const int* in_sizes, int n_in,
                              void* d_out, int out_size, void* d_ws, size_t ws_size,
                              hipStream_t stream)
{
  (void)in_sizes; (void)n_in; (void)out_size; (void)ws_size;
  const int*   cc   = (const int*)  d_in[0];
  const int*   cp   = (const int*)  d_in[1];
  const int*   cd   = (const int*)  d_in[2];
  const int*   cli  = (const int*)  d_in[3];
  const int*   clv  = (const int*)  d_in[4];
  const int*   cii  = (const int*)  d_in[5];
  const int*   civ  = (const int*)  d_in[6];
  const float* wgt  = (const float*)d_in[7];
  const float* age  = (const float*)d_in[8];
  const float* ec   = (const float*)d_in[9];
  const float* ep   = (const float*)d_in[10];
  const float* ed   = (const float*)d_in[11];
  const float* eli  = (const float*)d_in[12];
  const float* elv  = (const float*)d_in[13];
  const float* eii  = (const float*)d_in[14];
  const float* eiv  = (const float*)d_in[15];
  const float* mWih = (const float*)d_in[16];
  const float* mWhh = (const float*)d_in[17];
  const float* mbih = (const float*)d_in[18];
  const float* mbhh = (const float*)d_in[19];
  const float* vWih = (const float*)d_in[20];
  const float* vWhh = (const float*)d_in[21];
  const float* vbih = (const float*)d_in[22];
  const float* vbhh = (const float*)d_in[23];
  const float* Wself= (const float*)d_in[24];
  const float* Wmsg = (const float*)d_in[25];
  const float* fwW  = (const float*)d_in[26];
  const float* fwB  = (const float*)d_in[27];
  const float* faW  = (const float*)d_in[28];
  const float* faB  = (const float*)d_in[29];
  const float* Wp   = (const float*)d_in[30];
  const float* bp   = (const float*)d_in[31];
  float* out = (float*)d_out;
  float* ws  = (float*)d_ws;

  float* vis   = ws + OFF_VIS;
  float* mon   = ws + OFF_MON;
  float* w12   = ws + OFF_W12;
  float* wihTm = ws + OFF_WIHTM;
  float* wihTv = ws + OFF_WIHTV;
  float* xe    = ws + OFF_XE;
  float* gnn   = ws + OFF_GNN;
  float* gi    = ws + OFF_GI;
  float* last  = ws + OFF_LAST;
  float* vgi   = ws + OFF_VGI;
  float* vh    = ws + OFF_VH;

  k_prep<<<2496, 256, 0, stream>>>(Wself, Wmsg, mWih, vWih, wgt, age,
                                   fwW, fwB, faW, faB, w12, wihTm, wihTv, xe);
  k_vis <<<768, 128, 0, stream>>>(cc, cp, cd, ec, ep, ed, vis);
  k_mon <<<16384, 128, 0, stream>>>(cli, clv, cii, civ, eli, elv, eii, eiv, mon);
  k_gnn <<<512, 256, 0, stream>>>(vis, mon, w12, gnn);
  k_gi  <<<1536, 256, 0, stream>>>(gnn, wihTm, mbih, gi);
  k_mgru<<<256, 256, 0, stream>>>(gi, mWhh, mbhh, last);
  k_vgi <<<320, 384, 0, stream>>>(last, xe, wihTv, vbih, vgi);
  k_vgru<<<160, 768, 0, stream>>>(vgi, vWhh, vbhh, vh);
  k_head<<<38, 256, 0, stream>>>(vh, Wp, bp, out);
}

// Round 6
// 403.483 us; speedup vs baseline: 2.3227x; 1.3943x over previous
//
#include <hip/hip_runtime.h>
#include <math.h>

#define B_   16
#define V_   16
#define C_   64
#define M_   32
#define CM_  16
#define D_   128
#define OUT_ 600
#define NSEQ 256      // B*V
#define NROW 8192     // B*V*M

typedef __attribute__((ext_vector_type(8))) short bf16x8;
typedef __attribute__((ext_vector_type(4))) float f32x4;

__device__ __forceinline__ unsigned short f2bf(float x) {
  union { float f; unsigned u; } v; v.f = x;
  unsigned r = v.u + 0x7fff + ((v.u >> 16) & 1);   // RNE
  return (unsigned short)(r >> 16);
}

// ---- workspace layout (float units; bf16 arrays are short* views) ----
constexpr int OFF_VIS   = 0;                               // fp32 [3][256][128]
constexpr int OFF_VISB  = 98304;                           // bf16 [3][256][128]
constexpr int OFF_MONB  = 147456;                          // bf16 [2][8192][128]
constexpr int OFF_TOTB  = 1196032;                         // bf16 [2][8192][128]
constexpr int OFF_W12T  = 2244608;                         // bf16 [8][128n][256k]
constexpr int OFF_WIHB  = 2375680;                         // bf16 [5][384n][128k]
constexpr int OFF_WIHTV = 2498560;                         // fp32 [4][128][384]
constexpr int OFF_XE    = 2695168;                         // fp32 [2][256][128]
constexpr int OFF_GI    = 2760704;                         // fp32 [8][8192][384]
constexpr int OFF_LAST  = 27926528;                        // fp32 [8][256][128]
constexpr int OFF_VGI   = 28188672;                        // fp32 [10][256][384]
constexpr int OFF_VH    = 29171712;                        // fp32 [10][16][128]

// =====================================================================
// prep: bf16 combined GNN weights (B^T layout), bf16 mgru Wih (B^T = as-is),
// fp32 vgru Wih transpose, weight/age xe
// =====================================================================
__global__ __launch_bounds__(256) void k_prep(
    const float* __restrict__ Wself, const float* __restrict__ Wmsg,
    const float* __restrict__ mWih,  const float* __restrict__ vWih,
    const float* __restrict__ wgt,   const float* __restrict__ age,
    const float* __restrict__ fwW,   const float* __restrict__ fwB,
    const float* __restrict__ faW,   const float* __restrict__ faB,
    short* __restrict__ w12t, short* __restrict__ wihb,
    float* __restrict__ wihTv, float* __restrict__ xe)
{
  int bx = blockIdx.x, tid = threadIdx.x;
  if (bx < 1024) {                      // w12t[pt][n][k] = bf16 combined
    int lin = bx*256 + tid;             // < 262144
    int pt = lin >> 15, rem = lin & 32767;
    int n = rem >> 8, k = rem & 255;
    float v;
    if (k < 128) v = Wself[pt*16384 + k*128 + n] - Wmsg[pt*16384 + k*128 + n]*(1.f/3.f);
    else         v = Wmsg[pt*16384 + (k-128)*128 + n]*(1.f/3.f);
    w12t[lin] = (short)f2bf(v);
  } else if (bx < 1984) {               // wihb = bf16(mWih) elementwise ([n][k] already)
    int lin = (bx-1024)*256 + tid;      // < 245760
    wihb[lin] = (short)f2bf(mWih[lin]);
  } else if (bx < 2752) {               // vgru Wih transpose fp32 (for k_vgi)
    int lin = (bx-1984)*256 + tid;      // < 196608
    int g = lin / 49152, rem2 = lin % 49152;
    int k = rem2 / 384, j = rem2 % 384;
    wihTv[lin] = vWih[g*49152 + j*128 + k];
  } else {                              // xe for weight / age
    int lin = (bx-2752)*256 + tid;      // < 65536
    int which = lin >> 15, rem2 = lin & 32767;
    int n = rem2 >> 7, d = rem2 & 127;
    float x  = which ? age[n] : wgt[n];
    float Wv = which ? faW[d] : fwW[d];
    float bb = which ? faB[d] : fwB[d];
    xe[lin] = (x != 0.0f) ? (x*Wv + bb) : 0.0f;
  }
}

// =====================================================================
// visit-event embedding sum pools: vis fp32 + visb bf16
// =====================================================================
__global__ __launch_bounds__(128) void k_vis(
    const int* __restrict__ cc, const int* __restrict__ cp, const int* __restrict__ cd,
    const float* __restrict__ ec, const float* __restrict__ ep, const float* __restrict__ ed,
    float* __restrict__ vis, short* __restrict__ visb)
{
  int type = blockIdx.x >> 8;
  int bv   = blockIdx.x & 255;
  int d    = threadIdx.x;
  const int*   codes = (type==0) ? cc : (type==1) ? cp : cd;
  const float* emb   = (type==0) ? ec : (type==1) ? ep : ed;
  float acc = 0.f;
  for (int c = 0; c < C_; ++c) {
    int code = codes[bv*C_ + c];
    acc += emb[code*D_ + d];
  }
  vis [(type*NSEQ + bv)*D_ + d] = acc;
  visb[(type*NSEQ + bv)*D_ + d] = (short)f2bf(acc);
}

// =====================================================================
// monitor-event pools -> bf16 feat (monb) and bf16 total (totb = mon + sum vis)
// =====================================================================
__global__ __launch_bounds__(128) void k_mon(
    const int* __restrict__ cli, const int* __restrict__ clv,
    const int* __restrict__ cii, const int* __restrict__ civ,
    const float* __restrict__ eli, const float* __restrict__ elv,
    const float* __restrict__ eii, const float* __restrict__ eiv,
    const float* __restrict__ vis,
    short* __restrict__ monb, short* __restrict__ totb)
{
  int p   = blockIdx.x >> 13;
  int bvm = blockIdx.x & 8191;
  int d   = threadIdx.x;
  const int* ci = p ? cii : cli;  const int* cv = p ? civ : clv;
  const float* ei = p ? eii : eli; const float* ev = p ? eiv : elv;
  float acc = 0.f;
  #pragma unroll
  for (int c = 0; c < CM_; ++c) {
    int iv = ci[bvm*CM_ + c];
    int vv = cv[bvm*CM_ + c];
    acc += ei[iv*D_ + d] * ev[vv*D_ + d];
  }
  int bv = bvm >> 5;
  float vsum = vis[bv*D_ + d] + vis[(NSEQ + bv)*D_ + d] + vis[(2*NSEQ + bv)*D_ + d];
  monb[(p*NROW + bvm)*D_ + d] = (short)f2bf(acc);
  totb[(p*NROW + bvm)*D_ + d] = (short)f2bf(acc + vsum);
}

// =====================================================================
// FUSED GNN+GI (MFMA bf16): 512 blocks = (pt, 128-row tile) x 256 thr.
// Stage 1: Y[128][128] = relu( X[128][256] @ W12t^T ), X/W staged bf16 in
//   LDS stride-72 (bank-balanced); wave w owns (mg=w>>1, ng=w&1) quadrant.
// Y kept in LDS bf16 (stride 136). Stage 2: gi[128][384] = Y @ Wih^T + bih,
//   A-frags register-resident, B-frags streamed from L2-hot bf16 wihb.
// =====================================================================
__global__ __launch_bounds__(256, 2) void k_gg(
    const short* __restrict__ monb, const short* __restrict__ totb,
    const short* __restrict__ visb, const short* __restrict__ w12t,
    const short* __restrict__ wihb, const float* __restrict__ mbih,
    float* __restrict__ gi)
{
  const int pt = blockIdx.x >> 6;          // run 0..7
  const int rb = blockIdx.x & 63;
  const int p = pt >> 2, t = pt & 3;
  const int g = (pt % 4 == 0) ? (pt / 4) : (pt % 4 + 1);
  const int row0 = rb * 128;
  const int tid = threadIdx.x;
  const int w = tid >> 6, lane = tid & 63;
  const int c = lane & 15, q = lane >> 4;

  __shared__ short smem[2*128*72];         // 36864 B; Ys (128*136) aliases
  short (*Xs)[72]  = (short(*)[72])smem;
  short (*Ws)[72]  = (short(*)[72])(smem + 128*72);
  short (*Ys)[136] = (short(*)[136])smem;

  const int rowL = tid >> 1, kc = tid & 1;
  const int rowG = row0 + rowL;
  const int bv = rowG >> 5;
  const int mg = w >> 1, ng = w & 1;

  f32x4 acc1[4][4];
  #pragma unroll
  for (int mi = 0; mi < 4; ++mi)
    #pragma unroll
    for (int ni = 0; ni < 4; ++ni) acc1[mi][ni] = (f32x4){0.f,0.f,0.f,0.f};

  const short* featp = (t == 0) ? (monb + ((size_t)p*NROW + rowG)*128)
                                : (visb + ((size_t)(t-1)*NSEQ + bv)*128);
  const short* totp  = totb + ((size_t)p*NROW + rowG)*128;
  const short* wrow  = w12t + ((size_t)pt*128 + rowL)*256;

  #pragma unroll 1
  for (int ks = 0; ks < 4; ++ks) {
    __syncthreads();
    int kg = ks*64 + kc*32;
    const short* srcX = (kg < 128) ? (featp + kg) : (totp + (kg - 128));
    const short* srcW = wrow + kg;
    short* dX = &Xs[rowL][kc*32];
    short* dW = &Ws[rowL][kc*32];
    #pragma unroll
    for (int i = 0; i < 4; ++i) {
      *(bf16x8*)(dX + 8*i) = *(const bf16x8*)(srcX + 8*i);
      *(bf16x8*)(dW + 8*i) = *(const bf16x8*)(srcW + 8*i);
    }
    __syncthreads();
    #pragma unroll
    for (int kk = 0; kk < 2; ++kk) {
      bf16x8 af[4], bfr[4];
      #pragma unroll
      for (int mi = 0; mi < 4; ++mi)
        af[mi] = *(const bf16x8*)&Xs[(mg*4+mi)*16 + c][kk*32 + q*8];
      #pragma unroll
      for (int ni = 0; ni < 4; ++ni)
        bfr[ni] = *(const bf16x8*)&Ws[(ng*4+ni)*16 + c][kk*32 + q*8];
      #pragma unroll
      for (int mi = 0; mi < 4; ++mi)
        #pragma unroll
        for (int ni = 0; ni < 4; ++ni)
          acc1[mi][ni] = __builtin_amdgcn_mfma_f32_16x16x32_bf16(af[mi], bfr[ni], acc1[mi][ni], 0, 0, 0);
    }
  }
  __syncthreads();     // done reading Xs/Ws (Ys aliases them)

  // relu + C-layout (col=lane&15, row=(lane>>4)*4+reg) -> Ys[row][col] bf16
  #pragma unroll
  for (int mi = 0; mi < 4; ++mi)
    #pragma unroll
    for (int ni = 0; ni < 4; ++ni)
      #pragma unroll
      for (int reg = 0; reg < 4; ++reg)
        Ys[(mg*4+mi)*16 + q*4 + reg][(ng*4+ni)*16 + c] =
            (short)f2bf(fmaxf(acc1[mi][ni][reg], 0.f));
  __syncthreads();

  // ---- stage 2: gi = Y @ Wih^T + bih ----
  bf16x8 Af[2][4];
  #pragma unroll
  for (int mi = 0; mi < 2; ++mi)
    #pragma unroll
    for (int kt = 0; kt < 4; ++kt)
      Af[mi][kt] = *(const bf16x8*)&Ys[(w*2+mi)*16 + c][kt*32 + q*8];

  float bihv[24];
  #pragma unroll
  for (int nt = 0; nt < 24; ++nt)
    bihv[nt] = mbih[g*384 + nt*16 + c];

  float* gout = gi + ((size_t)pt*NROW + row0)*384;
  #pragma unroll 1
  for (int cn = 0; cn < 6; ++cn) {
    f32x4 acc2[2][4];
    #pragma unroll
    for (int mi = 0; mi < 2; ++mi)
      #pragma unroll
      for (int ni = 0; ni < 4; ++ni) acc2[mi][ni] = (f32x4){0.f,0.f,0.f,0.f};
    #pragma unroll
    for (int ni = 0; ni < 4; ++ni) {
      int n = (cn*4 + ni)*16 + c;
      const short* bp_ = wihb + ((size_t)g*384 + n)*128 + q*8;
      #pragma unroll
      for (int kt = 0; kt < 4; ++kt) {
        bf16x8 bfr = *(const bf16x8*)(bp_ + kt*32);
        #pragma unroll
        for (int mi = 0; mi < 2; ++mi)
          acc2[mi][ni] = __builtin_amdgcn_mfma_f32_16x16x32_bf16(Af[mi][kt], bfr, acc2[mi][ni], 0, 0, 0);
      }
    }
    #pragma unroll
    for (int mi = 0; mi < 2; ++mi)
      #pragma unroll
      for (int ni = 0; ni < 4; ++ni) {
        int col = (cn*4+ni)*16 + c;
        float bia = bihv[cn*4+ni];
        #pragma unroll
        for (int reg = 0; reg < 4; ++reg) {
          int row = (w*2+mi)*16 + q*4 + reg;
          gout[(size_t)row*384 + col] = acc2[mi][ni][reg] + bia;
        }
      }
  }
}

// =====================================================================
// monitor-level GRU v4 (MFMA) — unchanged from round 5 (verified).
// =====================================================================
__global__ __launch_bounds__(256, 1) void k_mgru(
    const float* __restrict__ gi, const float* __restrict__ mWhh,
    const float* __restrict__ mbhh, float* __restrict__ last)
{
  const int run = blockIdx.x >> 5, grp = blockIdx.x & 31;
  const int g = (run % 4 == 0) ? (run / 4) : (run % 4 + 1);
  const int tid = threadIdx.x;
  const int w = tid >> 6;
  const int lane = tid & 63;
  const int c = lane & 15, q = lane >> 4;

  __shared__ short hb[2][4][16][40];

  for (int idx = tid; idx < 2*4*16*40; idx += 256)
    ((short*)hb)[idx] = 0;

  bf16x8 bfrag[2][3][4];
  #pragma unroll
  for (int jj = 0; jj < 2; ++jj)
    #pragma unroll
    for (int gate = 0; gate < 3; ++gate) {
      int n = (w + jj*4 + gate*8)*16 + c;
      const float* wp = mWhh + (g*384 + n)*128 + q*8;
      #pragma unroll
      for (int kt = 0; kt < 4; ++kt) {
        float4 lo = *(const float4*)(wp + kt*32);
        float4 hi = *(const float4*)(wp + kt*32 + 4);
        bf16x8 t;
        t[0]=(short)f2bf(lo.x); t[1]=(short)f2bf(lo.y); t[2]=(short)f2bf(lo.z); t[3]=(short)f2bf(lo.w);
        t[4]=(short)f2bf(hi.x); t[5]=(short)f2bf(hi.y); t[6]=(short)f2bf(hi.z); t[7]=(short)f2bf(hi.w);
        bfrag[jj][gate][kt] = t;
      }
    }

  const int j0 = w*16 + c;
  const int j1 = (w+4)*16 + c;
  const float* bh = mbhh + g*384;
  float bh_[2][3];
  bh_[0][0]=bh[j0]; bh_[0][1]=bh[j0+128]; bh_[0][2]=bh[j0+256];
  bh_[1][0]=bh[j1]; bh_[1][1]=bh[j1+128]; bh_[1][2]=bh[j1+256];

  float hf[2][4] = {{0.f,0.f,0.f,0.f},{0.f,0.f,0.f,0.f}};
  const float* gib = gi + ((size_t)run*NROW + grp*8*32)*384;
  const bool act = (lane < 32);

  float gc[2][3][4];
  if (act) {
    #pragma unroll
    for (int jj = 0; jj < 2; ++jj) {
      int j = jj ? j1 : j0;
      #pragma unroll
      for (int gate = 0; gate < 3; ++gate)
        #pragma unroll
        for (int reg = 0; reg < 4; ++reg)
          gc[jj][gate][reg] = gib[((q*4+reg)*32 + 0)*384 + gate*128 + j];
    }
  }
  __syncthreads();

  int cur = 0;
  #pragma unroll 1
  for (int m = 0; m < 32; ++m) {
    bf16x8 a[4];
    #pragma unroll
    for (int kt = 0; kt < 4; ++kt)
      a[kt] = *(const bf16x8*)&hb[cur][kt][c][q*8];

    f32x4 acc[2][3];
    #pragma unroll
    for (int jj = 0; jj < 2; ++jj)
      #pragma unroll
      for (int gate = 0; gate < 3; ++gate) {
        f32x4 t = {0.f,0.f,0.f,0.f};
        #pragma unroll
        for (int kt = 0; kt < 4; ++kt)
          t = __builtin_amdgcn_mfma_f32_16x16x32_bf16(a[kt], bfrag[jj][gate][kt], t, 0, 0, 0);
        acc[jj][gate] = t;
      }

    float gn[2][3][4];
    if (act && m < 31) {
      #pragma unroll
      for (int jj = 0; jj < 2; ++jj) {
        int j = jj ? j1 : j0;
        #pragma unroll
        for (int gate = 0; gate < 3; ++gate)
          #pragma unroll
          for (int reg = 0; reg < 4; ++reg)
            gn[jj][gate][reg] = gib[((q*4+reg)*32 + (m+1))*384 + gate*128 + j];
      }
    }

    const int nxt = cur ^ 1;
    if (act) {
      #pragma unroll
      for (int jj = 0; jj < 2; ++jj) {
        int j = jj ? j1 : j0;
        int kt = j >> 5, kk = j & 31;
        #pragma unroll
        for (int reg = 0; reg < 4; ++reg) {
          int row = q*4 + reg;
          float rp = acc[jj][0][reg] + bh_[jj][0] + gc[jj][0][reg];
          float zp = acc[jj][1][reg] + bh_[jj][1] + gc[jj][1][reg];
          float hg = acc[jj][2][reg] + bh_[jj][2];
          float rr = 1.f/(1.f + __expf(-rp));
          float zz = 1.f/(1.f + __expf(-zp));
          float nn = tanhf(gc[jj][2][reg] + rr*hg);
          float hnew = (1.f - zz)*nn + zz*hf[jj][reg];
          hf[jj][reg] = hnew;
          hb[nxt][kt][row][kk] = (short)f2bf(hnew);
        }
      }
      if (m < 31) {
        #pragma unroll
        for (int jj = 0; jj < 2; ++jj)
          #pragma unroll
          for (int gate = 0; gate < 3; ++gate)
            #pragma unroll
            for (int reg = 0; reg < 4; ++reg)
              gc[jj][gate][reg] = gn[jj][gate][reg];
      }
    }
    __syncthreads();
    cur = nxt;
  }

  if (act) {
    #pragma unroll
    for (int jj = 0; jj < 2; ++jj) {
      int j = jj ? j1 : j0;
      #pragma unroll
      for (int reg = 0; reg < 4; ++reg)
        last[(run*NSEQ + grp*8 + q*4 + reg)*D_ + j] = hf[jj][reg];
    }
  }
}

// =====================================================================
// visit-level gi precompute (small GEMM), 10 runs x 256 rows
// =====================================================================
__global__ __launch_bounds__(384) void k_vgi(
    const float* __restrict__ last, const float* __restrict__ xe,
    const float* __restrict__ wihTv, const float* __restrict__ vbih,
    float* __restrict__ vgi)
{
  int run = blockIdx.x >> 5;
  int rblk = blockIdx.x & 31;
  int j = threadIdx.x;
  int vidx = (run < 4) ? 0 : (run < 8) ? 1 : (run - 6);
  __shared__ float Xs[8][128];
  const float* X = (run < 8) ? (last + run*NSEQ*D_) : (xe + (run-8)*NSEQ*D_);
  for (int idx = j; idx < 1024; idx += 384) {
    int s = idx >> 7, k = idx & 127;
    Xs[s][k] = X[(rblk*8 + s)*D_ + k];
  }
  __syncthreads();
  float acc[8];
  float bias = vbih[vidx*384 + j];
  #pragma unroll
  for (int s = 0; s < 8; ++s) acc[s] = bias;
  const float* W = wihTv + vidx*49152 + j;
  #pragma unroll 4
  for (int k = 0; k < 128; ++k) {
    float wv = W[k*384];
    #pragma unroll
    for (int s = 0; s < 8; ++s) acc[s] += Xs[s][k] * wv;
  }
  #pragma unroll
  for (int s = 0; s < 8; ++s)
    vgi[(run*NSEQ + rblk*8 + s)*384 + j] = acc[s];
}

// =====================================================================
// visit-level GRU v2.1 — unchanged from round 5 (verified).
// =====================================================================
__global__ __launch_bounds__(768) void k_vgru(
    const float* __restrict__ vgi, const float* __restrict__ vWhh,
    const float* __restrict__ vbhh, float* __restrict__ vh)
{
  int run = blockIdx.x >> 4, b = blockIdx.x & 15;
  int tid = threadIdx.x;
  int j = tid >> 1, kh = tid & 1;
  int vidx = (run < 4) ? 0 : (run < 8) ? 1 : (run - 6);
  float w[64];
  const float4* wrow = (const float4*)(vWhh + (vidx*384 + j)*128 + kh*64);
  #pragma unroll
  for (int k4 = 0; k4 < 16; ++k4) {
    float4 t4 = wrow[k4];
    w[4*k4] = t4.x; w[4*k4+1] = t4.y; w[4*k4+2] = t4.z; w[4*k4+3] = t4.w;
  }
  float bj = vbhh[vidx*384 + j];
  __shared__ __align__(16) float hsv[128];
  __shared__ float gh[384];
  if (tid < 128) hsv[tid] = 0.f;
  __syncthreads();
  const float* gib = vgi + (run*NSEQ + b*16)*384;
  #pragma unroll 1
  for (int v = 0; v < 16; ++v) {
    const float4* h4 = (const float4*)(hsv + kh*64);
    float p0 = 0.f, p1 = 0.f;
    #pragma unroll
    for (int k4 = 0; k4 < 8; ++k4) {
      float4 u0 = h4[k4], u1 = h4[k4+8];
      p0 += w[4*k4   ]*u0.x + w[4*k4+1 ]*u0.y + w[4*k4+2 ]*u0.z + w[4*k4+3 ]*u0.w;
      p1 += w[4*k4+32]*u1.x + w[4*k4+33]*u1.y + w[4*k4+34]*u1.z + w[4*k4+35]*u1.w;
    }
    float part = p0 + p1;
    part += __shfl_xor(part, 1);
    if (kh == 0) gh[j] = bj + ((j < 256) ? gib[v*384 + j] : 0.f) + part;
    __syncthreads();
    if (tid < 128) {
      float r = 1.f/(1.f + __expf(-gh[tid]));
      float z = 1.f/(1.f + __expf(-gh[tid+128]));
      float gin = gib[v*384 + 256 + tid];
      float n = tanhf(gin + r*gh[tid+256]);
      hsv[tid] = (1.f - z)*n + z*hsv[tid];
    }
    __syncthreads();
  }
  if (tid < 128) vh[(run*16 + b)*D_ + tid] = hsv[tid];
}

// =====================================================================
// head: out[b][o] = bp[o] + sum_c relu(pe[b][c]) * Wp[o][c]
// =====================================================================
__global__ __launch_bounds__(256) void k_head(
    const float* __restrict__ vh, const float* __restrict__ Wp,
    const float* __restrict__ bp, float* __restrict__ out)
{
  int idx = blockIdx.x*256 + threadIdx.x;
  if (idx >= OUT_*16) return;
  int o = idx >> 4, b = idx & 15;
  const int a1[7] = {0,1,2,3,4,8,9};
  const int a2[7] = {-1,5,6,7,-1,-1,-1};
  float acc = bp[o];
  for (int s = 0; s < 7; ++s) {
    const float* v1 = vh + (a1[s]*16 + b)*D_;
    const float* v2 = (a2[s] >= 0) ? (vh + (a2[s]*16 + b)*D_) : nullptr;
    const float* w = Wp + o*896 + s*D_;
    #pragma unroll 4
    for (int d2 = 0; d2 < D_; ++d2) {
      float v = v1[d2] + (v2 ? v2[d2] : 0.f);
      v = v > 0.f ? v : 0.f;
      acc += v * w[d2];
    }
  }
  out[b*OUT_ + o] = acc;
}

// =====================================================================
extern "C" void kernel_launch(void* const* d_in, const int* in_sizes, int n_in,
                              void* d_out, int out_size, void* d_ws, size_t ws_size,
                              hipStream_t stream)
{
  (void)in_sizes; (void)n_in; (void)out_size; (void)ws_size;
  const int*   cc   = (const int*)  d_in[0];
  const int*   cp   = (const int*)  d_in[1];
  const int*   cd   = (const int*)  d_in[2];
  const int*   cli  = (const int*)  d_in[3];
  const int*   clv  = (const int*)  d_in[4];
  const int*   cii  = (const int*)  d_in[5];
  const int*   civ  = (const int*)  d_in[6];
  const float* wgt  = (const float*)d_in[7];
  const float* age  = (const float*)d_in[8];
  const float* ec   = (const float*)d_in[9];
  const float* ep   = (const float*)d_in[10];
  const float* ed   = (const float*)d_in[11];
  const float* eli  = (const float*)d_in[12];
  const float* elv  = (const float*)d_in[13];
  const float* eii  = (const float*)d_in[14];
  const float* eiv  = (const float*)d_in[15];
  const float* mWih = (const float*)d_in[16];
  const float* mWhh = (const float*)d_in[17];
  const float* mbih = (const float*)d_in[18];
  const float* mbhh = (const float*)d_in[19];
  const float* vWih = (const float*)d_in[20];
  const float* vWhh = (const float*)d_in[21];
  const float* vbih = (const float*)d_in[22];
  const float* vbhh = (const float*)d_in[23];
  const float* Wself= (const float*)d_in[24];
  const float* Wmsg = (const float*)d_in[25];
  const float* fwW  = (const float*)d_in[26];
  const float* fwB  = (const float*)d_in[27];
  const float* faW  = (const float*)d_in[28];
  const float* faB  = (const float*)d_in[29];
  const float* Wp   = (const float*)d_in[30];
  const float* bp   = (const float*)d_in[31];
  float* out = (float*)d_out;
  float* ws  = (float*)d_ws;

  float* vis   = ws + OFF_VIS;
  short* visb  = (short*)(ws + OFF_VISB);
  short* monb  = (short*)(ws + OFF_MONB);
  short* totb  = (short*)(ws + OFF_TOTB);
  short* w12t  = (short*)(ws + OFF_W12T);
  short* wihb  = (short*)(ws + OFF_WIHB);
  float* wihTv = ws + OFF_WIHTV;
  float* xe    = ws + OFF_XE;
  float* gi    = ws + OFF_GI;
  float* last  = ws + OFF_LAST;
  float* vgi   = ws + OFF_VGI;
  float* vh    = ws + OFF_VH;

  k_prep<<<3008, 256, 0, stream>>>(Wself, Wmsg, mWih, vWih, wgt, age,
                                   fwW, fwB, faW, faB, w12t, wihb, wihTv, xe);
  k_vis <<<768, 128, 0, stream>>>(cc, cp, cd, ec, ep, ed, vis, visb);
  k_mon <<<16384, 128, 0, stream>>>(cli, clv, cii, civ, eli, elv, eii, eiv,
                                    vis, monb, totb);
  k_gg  <<<512, 256, 0, stream>>>(monb, totb, visb, w12t, wihb, mbih, gi);
  k_mgru<<<256, 256, 0, stream>>>(gi, mWhh, mbhh, last);
  k_vgi <<<320, 384, 0, stream>>>(last, xe, wihTv, vbih, vgi);
  k_vgru<<<160, 768, 0, stream>>>(vgi, vWhh, vbhh, vh);
  k_head<<<38, 256, 0, stream>>>(vh, Wp, bp, out);
}

// Round 7
// 344.843 us; speedup vs baseline: 2.7176x; 1.1700x over previous
//
#include <hip/hip_runtime.h>
#include <math.h>

#define B_   16
#define V_   16
#define C_   64
#define M_   32
#define CM_  16
#define D_   128
#define OUT_ 600
#define NSEQ 256      // B*V
#define NROW 8192     // B*V*M

typedef __attribute__((ext_vector_type(8))) short bf16x8;
typedef __attribute__((ext_vector_type(4))) float f32x4;

__device__ __forceinline__ unsigned short f2bf(float x) {
  union { float f; unsigned u; } v; v.f = x;
  unsigned r = v.u + 0x7fff + ((v.u >> 16) & 1);   // RNE
  return (unsigned short)(r >> 16);
}

// ---- workspace layout (float units; bf16 arrays are short* views) ----
constexpr int OFF_VIS   = 0;                               // fp32 [3][256][128]
constexpr int OFF_VISB  = 98304;                           // bf16 [3][256][128]
constexpr int OFF_MONB  = 147456;                          // bf16 [2][8192][128]
constexpr int OFF_TOTB  = 1196032;                         // bf16 [2][8192][128]
constexpr int OFF_W12T  = 2244608;                         // bf16 [8][128n][256k]
constexpr int OFF_WIHB  = 2375680;                         // bf16 [5][384n][128k]
constexpr int OFF_WIHTV = 2498560;                         // fp32 [4][128][384]
constexpr int OFF_XE    = 2695168;                         // fp32 [2][256][128]
constexpr int OFF_GI    = 2760704;                         // fp32 [8][8192][384]
constexpr int OFF_LAST  = 27926528;                        // fp32 [8][256][128]
constexpr int OFF_VGI   = 28188672;                        // fp32 [10][256][384]
constexpr int OFF_VH    = 29171712;                        // fp32 [10][16][128]

// =====================================================================
// prep: bf16 combined GNN weights (B^T layout), bf16 mgru Wih (B^T = as-is),
// fp32 vgru Wih transpose, weight/age xe
// =====================================================================
__global__ __launch_bounds__(256) void k_prep(
    const float* __restrict__ Wself, const float* __restrict__ Wmsg,
    const float* __restrict__ mWih,  const float* __restrict__ vWih,
    const float* __restrict__ wgt,   const float* __restrict__ age,
    const float* __restrict__ fwW,   const float* __restrict__ fwB,
    const float* __restrict__ faW,   const float* __restrict__ faB,
    short* __restrict__ w12t, short* __restrict__ wihb,
    float* __restrict__ wihTv, float* __restrict__ xe)
{
  int bx = blockIdx.x, tid = threadIdx.x;
  if (bx < 1024) {                      // w12t[pt][n][k] = bf16 combined
    int lin = bx*256 + tid;             // < 262144
    int pt = lin >> 15, rem = lin & 32767;
    int n = rem >> 8, k = rem & 255;
    float v;
    if (k < 128) v = Wself[pt*16384 + k*128 + n] - Wmsg[pt*16384 + k*128 + n]*(1.f/3.f);
    else         v = Wmsg[pt*16384 + (k-128)*128 + n]*(1.f/3.f);
    w12t[lin] = (short)f2bf(v);
  } else if (bx < 1984) {               // wihb = bf16(mWih) elementwise ([n][k] already)
    int lin = (bx-1024)*256 + tid;      // < 245760
    wihb[lin] = (short)f2bf(mWih[lin]);
  } else if (bx < 2752) {               // vgru Wih transpose fp32 (for k_vgi)
    int lin = (bx-1984)*256 + tid;      // < 196608
    int g = lin / 49152, rem2 = lin % 49152;
    int k = rem2 / 384, j = rem2 % 384;
    wihTv[lin] = vWih[g*49152 + j*128 + k];
  } else {                              // xe for weight / age
    int lin = (bx-2752)*256 + tid;      // < 65536
    int which = lin >> 15, rem2 = lin & 32767;
    int n = rem2 >> 7, d = rem2 & 127;
    float x  = which ? age[n] : wgt[n];
    float Wv = which ? faW[d] : fwW[d];
    float bb = which ? faB[d] : fwB[d];
    xe[lin] = (x != 0.0f) ? (x*Wv + bb) : 0.0f;
  }
}

// =====================================================================
// visit-event embedding sum pools: vis fp32 + visb bf16
// =====================================================================
__global__ __launch_bounds__(128) void k_vis(
    const int* __restrict__ cc, const int* __restrict__ cp, const int* __restrict__ cd,
    const float* __restrict__ ec, const float* __restrict__ ep, const float* __restrict__ ed,
    float* __restrict__ vis, short* __restrict__ visb)
{
  int type = blockIdx.x >> 8;
  int bv   = blockIdx.x & 255;
  int d    = threadIdx.x;
  const int*   codes = (type==0) ? cc : (type==1) ? cp : cd;
  const float* emb   = (type==0) ? ec : (type==1) ? ep : ed;
  float acc = 0.f;
  for (int c = 0; c < C_; ++c) {
    int code = codes[bv*C_ + c];
    acc += emb[code*D_ + d];
  }
  vis [(type*NSEQ + bv)*D_ + d] = acc;
  visb[(type*NSEQ + bv)*D_ + d] = (short)f2bf(acc);
}

// =====================================================================
// monitor-event pools -> bf16 feat (monb) and bf16 total (totb = mon + sum vis)
// =====================================================================
__global__ __launch_bounds__(128) void k_mon(
    const int* __restrict__ cli, const int* __restrict__ clv,
    const int* __restrict__ cii, const int* __restrict__ civ,
    const float* __restrict__ eli, const float* __restrict__ elv,
    const float* __restrict__ eii, const float* __restrict__ eiv,
    const float* __restrict__ vis,
    short* __restrict__ monb, short* __restrict__ totb)
{
  int p   = blockIdx.x >> 13;
  int bvm = blockIdx.x & 8191;
  int d   = threadIdx.x;
  const int* ci = p ? cii : cli;  const int* cv = p ? civ : clv;
  const float* ei = p ? eii : eli; const float* ev = p ? eiv : elv;
  float acc = 0.f;
  #pragma unroll
  for (int c = 0; c < CM_; ++c) {
    int iv = ci[bvm*CM_ + c];
    int vv = cv[bvm*CM_ + c];
    acc += ei[iv*D_ + d] * ev[vv*D_ + d];
  }
  int bv = bvm >> 5;
  float vsum = vis[bv*D_ + d] + vis[(NSEQ + bv)*D_ + d] + vis[(2*NSEQ + bv)*D_ + d];
  monb[(p*NROW + bvm)*D_ + d] = (short)f2bf(acc);
  totb[(p*NROW + bvm)*D_ + d] = (short)f2bf(acc + vsum);
}

// =====================================================================
// FUSED GNN+GI (MFMA bf16) — unchanged from round 6 (verified).
// =====================================================================
__global__ __launch_bounds__(256, 2) void k_gg(
    const short* __restrict__ monb, const short* __restrict__ totb,
    const short* __restrict__ visb, const short* __restrict__ w12t,
    const short* __restrict__ wihb, const float* __restrict__ mbih,
    float* __restrict__ gi)
{
  const int pt = blockIdx.x >> 6;          // run 0..7
  const int rb = blockIdx.x & 63;
  const int p = pt >> 2, t = pt & 3;
  const int g = (pt % 4 == 0) ? (pt / 4) : (pt % 4 + 1);
  const int row0 = rb * 128;
  const int tid = threadIdx.x;
  const int w = tid >> 6, lane = tid & 63;
  const int c = lane & 15, q = lane >> 4;

  __shared__ short smem[2*128*72];         // 36864 B; Ys (128*136) aliases
  short (*Xs)[72]  = (short(*)[72])smem;
  short (*Ws)[72]  = (short(*)[72])(smem + 128*72);
  short (*Ys)[136] = (short(*)[136])smem;

  const int rowL = tid >> 1, kc = tid & 1;
  const int rowG = row0 + rowL;
  const int bv = rowG >> 5;
  const int mg = w >> 1, ng = w & 1;

  f32x4 acc1[4][4];
  #pragma unroll
  for (int mi = 0; mi < 4; ++mi)
    #pragma unroll
    for (int ni = 0; ni < 4; ++ni) acc1[mi][ni] = (f32x4){0.f,0.f,0.f,0.f};

  const short* featp = (t == 0) ? (monb + ((size_t)p*NROW + rowG)*128)
                                : (visb + ((size_t)(t-1)*NSEQ + bv)*128);
  const short* totp  = totb + ((size_t)p*NROW + rowG)*128;
  const short* wrow  = w12t + ((size_t)pt*128 + rowL)*256;

  #pragma unroll 1
  for (int ks = 0; ks < 4; ++ks) {
    __syncthreads();
    int kg = ks*64 + kc*32;
    const short* srcX = (kg < 128) ? (featp + kg) : (totp + (kg - 128));
    const short* srcW = wrow + kg;
    short* dX = &Xs[rowL][kc*32];
    short* dW = &Ws[rowL][kc*32];
    #pragma unroll
    for (int i = 0; i < 4; ++i) {
      *(bf16x8*)(dX + 8*i) = *(const bf16x8*)(srcX + 8*i);
      *(bf16x8*)(dW + 8*i) = *(const bf16x8*)(srcW + 8*i);
    }
    __syncthreads();
    #pragma unroll
    for (int kk = 0; kk < 2; ++kk) {
      bf16x8 af[4], bfr[4];
      #pragma unroll
      for (int mi = 0; mi < 4; ++mi)
        af[mi] = *(const bf16x8*)&Xs[(mg*4+mi)*16 + c][kk*32 + q*8];
      #pragma unroll
      for (int ni = 0; ni < 4; ++ni)
        bfr[ni] = *(const bf16x8*)&Ws[(ng*4+ni)*16 + c][kk*32 + q*8];
      #pragma unroll
      for (int mi = 0; mi < 4; ++mi)
        #pragma unroll
        for (int ni = 0; ni < 4; ++ni)
          acc1[mi][ni] = __builtin_amdgcn_mfma_f32_16x16x32_bf16(af[mi], bfr[ni], acc1[mi][ni], 0, 0, 0);
    }
  }
  __syncthreads();     // done reading Xs/Ws (Ys aliases them)

  // relu + C-layout (col=lane&15, row=(lane>>4)*4+reg) -> Ys[row][col] bf16
  #pragma unroll
  for (int mi = 0; mi < 4; ++mi)
    #pragma unroll
    for (int ni = 0; ni < 4; ++ni)
      #pragma unroll
      for (int reg = 0; reg < 4; ++reg)
        Ys[(mg*4+mi)*16 + q*4 + reg][(ng*4+ni)*16 + c] =
            (short)f2bf(fmaxf(acc1[mi][ni][reg], 0.f));
  __syncthreads();

  // ---- stage 2: gi = Y @ Wih^T + bih ----
  bf16x8 Af[2][4];
  #pragma unroll
  for (int mi = 0; mi < 2; ++mi)
    #pragma unroll
    for (int kt = 0; kt < 4; ++kt)
      Af[mi][kt] = *(const bf16x8*)&Ys[(w*2+mi)*16 + c][kt*32 + q*8];

  float bihv[24];
  #pragma unroll
  for (int nt = 0; nt < 24; ++nt)
    bihv[nt] = mbih[g*384 + nt*16 + c];

  float* gout = gi + ((size_t)pt*NROW + row0)*384;
  #pragma unroll 1
  for (int cn = 0; cn < 6; ++cn) {
    f32x4 acc2[2][4];
    #pragma unroll
    for (int mi = 0; mi < 2; ++mi)
      #pragma unroll
      for (int ni = 0; ni < 4; ++ni) acc2[mi][ni] = (f32x4){0.f,0.f,0.f,0.f};
    #pragma unroll
    for (int ni = 0; ni < 4; ++ni) {
      int n = (cn*4 + ni)*16 + c;
      const short* bp_ = wihb + ((size_t)g*384 + n)*128 + q*8;
      #pragma unroll
      for (int kt = 0; kt < 4; ++kt) {
        bf16x8 bfr = *(const bf16x8*)(bp_ + kt*32);
        #pragma unroll
        for (int mi = 0; mi < 2; ++mi)
          acc2[mi][ni] = __builtin_amdgcn_mfma_f32_16x16x32_bf16(Af[mi][kt], bfr, acc2[mi][ni], 0, 0, 0);
      }
    }
    #pragma unroll
    for (int mi = 0; mi < 2; ++mi)
      #pragma unroll
      for (int ni = 0; ni < 4; ++ni) {
        int col = (cn*4+ni)*16 + c;
        float bia = bihv[cn*4+ni];
        #pragma unroll
        for (int reg = 0; reg < 4; ++reg) {
          int row = (w*2+mi)*16 + q*4 + reg;
          gout[(size_t)row*384 + col] = acc2[mi][ni][reg] + bia;
        }
      }
  }
}

// =====================================================================
// monitor-level GRU v4 (MFMA) — unchanged from round 5 (verified).
// =====================================================================
__global__ __launch_bounds__(256, 1) void k_mgru(
    const float* __restrict__ gi, const float* __restrict__ mWhh,
    const float* __restrict__ mbhh, float* __restrict__ last)
{
  const int run = blockIdx.x >> 5, grp = blockIdx.x & 31;
  const int g = (run % 4 == 0) ? (run / 4) : (run % 4 + 1);
  const int tid = threadIdx.x;
  const int w = tid >> 6;
  const int lane = tid & 63;
  const int c = lane & 15, q = lane >> 4;

  __shared__ short hb[2][4][16][40];

  for (int idx = tid; idx < 2*4*16*40; idx += 256)
    ((short*)hb)[idx] = 0;

  bf16x8 bfrag[2][3][4];
  #pragma unroll
  for (int jj = 0; jj < 2; ++jj)
    #pragma unroll
    for (int gate = 0; gate < 3; ++gate) {
      int n = (w + jj*4 + gate*8)*16 + c;
      const float* wp = mWhh + (g*384 + n)*128 + q*8;
      #pragma unroll
      for (int kt = 0; kt < 4; ++kt) {
        float4 lo = *(const float4*)(wp + kt*32);
        float4 hi = *(const float4*)(wp + kt*32 + 4);
        bf16x8 t;
        t[0]=(short)f2bf(lo.x); t[1]=(short)f2bf(lo.y); t[2]=(short)f2bf(lo.z); t[3]=(short)f2bf(lo.w);
        t[4]=(short)f2bf(hi.x); t[5]=(short)f2bf(hi.y); t[6]=(short)f2bf(hi.z); t[7]=(short)f2bf(hi.w);
        bfrag[jj][gate][kt] = t;
      }
    }

  const int j0 = w*16 + c;
  const int j1 = (w+4)*16 + c;
  const float* bh = mbhh + g*384;
  float bh_[2][3];
  bh_[0][0]=bh[j0]; bh_[0][1]=bh[j0+128]; bh_[0][2]=bh[j0+256];
  bh_[1][0]=bh[j1]; bh_[1][1]=bh[j1+128]; bh_[1][2]=bh[j1+256];

  float hf[2][4] = {{0.f,0.f,0.f,0.f},{0.f,0.f,0.f,0.f}};
  const float* gib = gi + ((size_t)run*NROW + grp*8*32)*384;
  const bool act = (lane < 32);

  float gc[2][3][4];
  if (act) {
    #pragma unroll
    for (int jj = 0; jj < 2; ++jj) {
      int j = jj ? j1 : j0;
      #pragma unroll
      for (int gate = 0; gate < 3; ++gate)
        #pragma unroll
        for (int reg = 0; reg < 4; ++reg)
          gc[jj][gate][reg] = gib[((q*4+reg)*32 + 0)*384 + gate*128 + j];
    }
  }
  __syncthreads();

  int cur = 0;
  #pragma unroll 1
  for (int m = 0; m < 32; ++m) {
    bf16x8 a[4];
    #pragma unroll
    for (int kt = 0; kt < 4; ++kt)
      a[kt] = *(const bf16x8*)&hb[cur][kt][c][q*8];

    f32x4 acc[2][3];
    #pragma unroll
    for (int jj = 0; jj < 2; ++jj)
      #pragma unroll
      for (int gate = 0; gate < 3; ++gate) {
        f32x4 t = {0.f,0.f,0.f,0.f};
        #pragma unroll
        for (int kt = 0; kt < 4; ++kt)
          t = __builtin_amdgcn_mfma_f32_16x16x32_bf16(a[kt], bfrag[jj][gate][kt], t, 0, 0, 0);
        acc[jj][gate] = t;
      }

    float gn[2][3][4];
    if (act && m < 31) {
      #pragma unroll
      for (int jj = 0; jj < 2; ++jj) {
        int j = jj ? j1 : j0;
        #pragma unroll
        for (int gate = 0; gate < 3; ++gate)
          #pragma unroll
          for (int reg = 0; reg < 4; ++reg)
            gn[jj][gate][reg] = gib[((q*4+reg)*32 + (m+1))*384 + gate*128 + j];
      }
    }

    const int nxt = cur ^ 1;
    if (act) {
      #pragma unroll
      for (int jj = 0; jj < 2; ++jj) {
        int j = jj ? j1 : j0;
        int kt = j >> 5, kk = j & 31;
        #pragma unroll
        for (int reg = 0; reg < 4; ++reg) {
          int row = q*4 + reg;
          float rp = acc[jj][0][reg] + bh_[jj][0] + gc[jj][0][reg];
          float zp = acc[jj][1][reg] + bh_[jj][1] + gc[jj][1][reg];
          float hg = acc[jj][2][reg] + bh_[jj][2];
          float rr = 1.f/(1.f + __expf(-rp));
          float zz = 1.f/(1.f + __expf(-zp));
          float nn = tanhf(gc[jj][2][reg] + rr*hg);
          float hnew = (1.f - zz)*nn + zz*hf[jj][reg];
          hf[jj][reg] = hnew;
          hb[nxt][kt][row][kk] = (short)f2bf(hnew);
        }
      }
      if (m < 31) {
        #pragma unroll
        for (int jj = 0; jj < 2; ++jj)
          #pragma unroll
          for (int gate = 0; gate < 3; ++gate)
            #pragma unroll
            for (int reg = 0; reg < 4; ++reg)
              gc[jj][gate][reg] = gn[jj][gate][reg];
      }
    }
    __syncthreads();
    cur = nxt;
  }

  if (act) {
    #pragma unroll
    for (int jj = 0; jj < 2; ++jj) {
      int j = jj ? j1 : j0;
      #pragma unroll
      for (int reg = 0; reg < 4; ++reg)
        last[(run*NSEQ + grp*8 + q*4 + reg)*D_ + j] = hf[jj][reg];
    }
  }
}

// =====================================================================
// visit-level gi precompute (small GEMM), 10 runs x 256 rows
// =====================================================================
__global__ __launch_bounds__(384) void k_vgi(
    const float* __restrict__ last, const float* __restrict__ xe,
    const float* __restrict__ wihTv, const float* __restrict__ vbih,
    float* __restrict__ vgi)
{
  int run = blockIdx.x >> 5;
  int rblk = blockIdx.x & 31;
  int j = threadIdx.x;
  int vidx = (run < 4) ? 0 : (run < 8) ? 1 : (run - 6);
  __shared__ float Xs[8][128];
  const float* X = (run < 8) ? (last + run*NSEQ*D_) : (xe + (run-8)*NSEQ*D_);
  for (int idx = j; idx < 1024; idx += 384) {
    int s = idx >> 7, k = idx & 127;
    Xs[s][k] = X[(rblk*8 + s)*D_ + k];
  }
  __syncthreads();
  float acc[8];
  float bias = vbih[vidx*384 + j];
  #pragma unroll
  for (int s = 0; s < 8; ++s) acc[s] = bias;
  const float* W = wihTv + vidx*49152 + j;
  #pragma unroll 4
  for (int k = 0; k < 128; ++k) {
    float wv = W[k*384];
    #pragma unroll
    for (int s = 0; s < 8; ++s) acc[s] += Xs[s][k] * wv;
  }
  #pragma unroll
  for (int s = 0; s < 8; ++s)
    vgi[(run*NSEQ + rblk*8 + s)*384 + j] = acc[s];
}

// =====================================================================
// visit-level GRU v2.1 — unchanged (verified).
// =====================================================================
__global__ __launch_bounds__(768) void k_vgru(
    const float* __restrict__ vgi, const float* __restrict__ vWhh,
    const float* __restrict__ vbhh, float* __restrict__ vh)
{
  int run = blockIdx.x >> 4, b = blockIdx.x & 15;
  int tid = threadIdx.x;
  int j = tid >> 1, kh = tid & 1;
  int vidx = (run < 4) ? 0 : (run < 8) ? 1 : (run - 6);
  float w[64];
  const float4* wrow = (const float4*)(vWhh + (vidx*384 + j)*128 + kh*64);
  #pragma unroll
  for (int k4 = 0; k4 < 16; ++k4) {
    float4 t4 = wrow[k4];
    w[4*k4] = t4.x; w[4*k4+1] = t4.y; w[4*k4+2] = t4.z; w[4*k4+3] = t4.w;
  }
  float bj = vbhh[vidx*384 + j];
  __shared__ __align__(16) float hsv[128];
  __shared__ float gh[384];
  if (tid < 128) hsv[tid] = 0.f;
  __syncthreads();
  const float* gib = vgi + (run*NSEQ + b*16)*384;
  #pragma unroll 1
  for (int v = 0; v < 16; ++v) {
    const float4* h4 = (const float4*)(hsv + kh*64);
    float p0 = 0.f, p1 = 0.f;
    #pragma unroll
    for (int k4 = 0; k4 < 8; ++k4) {
      float4 u0 = h4[k4], u1 = h4[k4+8];
      p0 += w[4*k4   ]*u0.x + w[4*k4+1 ]*u0.y + w[4*k4+2 ]*u0.z + w[4*k4+3 ]*u0.w;
      p1 += w[4*k4+32]*u1.x + w[4*k4+33]*u1.y + w[4*k4+34]*u1.z + w[4*k4+35]*u1.w;
    }
    float part = p0 + p1;
    part += __shfl_xor(part, 1);
    if (kh == 0) gh[j] = bj + ((j < 256) ? gib[v*384 + j] : 0.f) + part;
    __syncthreads();
    if (tid < 128) {
      float r = 1.f/(1.f + __expf(-gh[tid]));
      float z = 1.f/(1.f + __expf(-gh[tid+128]));
      float gin = gib[v*384 + 256 + tid];
      float n = tanhf(gin + r*gh[tid+256]);
      hsv[tid] = (1.f - z)*n + z*hsv[tid];
    }
    __syncthreads();
  }
  if (tid < 128) vh[(run*16 + b)*D_ + tid] = hsv[tid];
}

// =====================================================================
// head v2: 600 blocks (one per output col o) x 256 threads.
// pe[16][896] (relu'd concat) staged in LDS pitch-899 (bank-spread) +
// Wp row in LDS; thread (b, kc) reduces a 56-wide K-chunk; padded-LDS
// tree across kc. Replaces the 38-block / 6272-serial-FMA version that
// ran at 1% VALUBusy for 110 us.
// =====================================================================
__global__ __launch_bounds__(256) void k_head(
    const float* __restrict__ vh, const float* __restrict__ Wp,
    const float* __restrict__ bp, float* __restrict__ out)
{
  const int o = blockIdx.x;
  const int tid = threadIdx.x;
  __shared__ float peL[16*899];
  __shared__ float wL[896];
  __shared__ float red[16][17];

  const int a1[7] = {0,1,2,3,4,8,9};
  const int a2[7] = {-1,5,6,7,-1,-1,-1};

  for (int idx = tid; idx < 16*896; idx += 256) {
    int b = idx / 896, cc2 = idx % 896;
    int s = cc2 >> 7, d = cc2 & 127;
    float v = vh[(a1[s]*16 + b)*D_ + d];
    int s2 = a2[s];
    if (s2 >= 0) v += vh[(s2*16 + b)*D_ + d];
    peL[b*899 + cc2] = fmaxf(v, 0.f);
  }
  for (int idx = tid; idx < 896; idx += 256)
    wL[idx] = Wp[o*896 + idx];
  __syncthreads();

  const int b = tid & 15, kc = tid >> 4;
  const float* pb = peL + b*899 + kc*56;
  const float* wb = wL + kc*56;
  float acc = 0.f;
  #pragma unroll
  for (int i = 0; i < 56; ++i)
    acc += pb[i] * wb[i];
  red[kc][b] = acc;
  __syncthreads();
  if (tid < 16) {
    float s = 0.f;
    #pragma unroll
    for (int k = 0; k < 16; ++k) s += red[k][tid];
    out[tid*OUT_ + o] = s + bp[o];
  }
}

// =====================================================================
extern "C" void kernel_launch(void* const* d_in, const int* in_sizes, int n_in,
                              void* d_out, int out_size, void* d_ws, size_t ws_size,
                              hipStream_t stream)
{
  (void)in_sizes; (void)n_in; (void)out_size; (void)ws_size;
  const int*   cc   = (const int*)  d_in[0];
  const int*   cp   = (const int*)  d_in[1];
  const int*   cd   = (const int*)  d_in[2];
  const int*   cli  = (const int*)  d_in[3];
  const int*   clv  = (const int*)  d_in[4];
  const int*   cii  = (const int*)  d_in[5];
  const int*   civ  = (const int*)  d_in[6];
  const float* wgt  = (const float*)d_in[7];
  const float* age  = (const float*)d_in[8];
  const float* ec   = (const float*)d_in[9];
  const float* ep   = (const float*)d_in[10];
  const float* ed   = (const float*)d_in[11];
  const float* eli  = (const float*)d_in[12];
  const float* elv  = (const float*)d_in[13];
  const float* eii  = (const float*)d_in[14];
  const float* eiv  = (const float*)d_in[15];
  const float* mWih = (const float*)d_in[16];
  const float* mWhh = (const float*)d_in[17];
  const float* mbih = (const float*)d_in[18];
  const float* mbhh = (const float*)d_in[19];
  const float* vWih = (const float*)d_in[20];
  const float* vWhh = (const float*)d_in[21];
  const float* vbih = (const float*)d_in[22];
  const float* vbhh = (const float*)d_in[23];
  const float* Wself= (const float*)d_in[24];
  const float* Wmsg = (const float*)d_in[25];
  const float* fwW  = (const float*)d_in[26];
  const float* fwB  = (const float*)d_in[27];
  const float* faW  = (const float*)d_in[28];
  const float* faB  = (const float*)d_in[29];
  const float* Wp   = (const float*)d_in[30];
  const float* bp   = (const float*)d_in[31];
  float* out = (float*)d_out;
  float* ws  = (float*)d_ws;

  float* vis   = ws + OFF_VIS;
  short* visb  = (short*)(ws + OFF_VISB);
  short* monb  = (short*)(ws + OFF_MONB);
  short* totb  = (short*)(ws + OFF_TOTB);
  short* w12t  = (short*)(ws + OFF_W12T);
  short* wihb  = (short*)(ws + OFF_WIHB);
  float* wihTv = ws + OFF_WIHTV;
  float* xe    = ws + OFF_XE;
  float* gi    = ws + OFF_GI;
  float* last  = ws + OFF_LAST;
  float* vgi   = ws + OFF_VGI;
  float* vh    = ws + OFF_VH;

  k_prep<<<3008, 256, 0, stream>>>(Wself, Wmsg, mWih, vWih, wgt, age,
                                   fwW, fwB, faW, faB, w12t, wihb, wihTv, xe);
  k_vis <<<768, 128, 0, stream>>>(cc, cp, cd, ec, ep, ed, vis, visb);
  k_mon <<<16384, 128, 0, stream>>>(cli, clv, cii, civ, eli, elv, eii, eiv,
                                    vis, monb, totb);
  k_gg  <<<512, 256, 0, stream>>>(monb, totb, visb, w12t, wihb, mbih, gi);
  k_mgru<<<256, 256, 0, stream>>>(gi, mWhh, mbhh, last);
  k_vgi <<<320, 384, 0, stream>>>(last, xe, wihTv, vbih, vgi);
  k_vgru<<<160, 768, 0, stream>>>(vgi, vWhh, vbhh, vh);
  k_head<<<600, 256, 0, stream>>>(vh, Wp, bp, out);
}

// Round 8
// 326.293 us; speedup vs baseline: 2.8721x; 1.0569x over previous
//
#include <hip/hip_runtime.h>
#include <math.h>

#define B_   16
#define V_   16
#define C_   64
#define M_   32
#define CM_  16
#define D_   128
#define OUT_ 600
#define NSEQ 256      // B*V
#define NROW 8192     // B*V*M

typedef __attribute__((ext_vector_type(8))) short bf16x8;
typedef __attribute__((ext_vector_type(4))) float f32x4;

__device__ __forceinline__ unsigned short f2bf(float x) {
  union { float f; unsigned u; } v; v.f = x;
  unsigned r = v.u + 0x7fff + ((v.u >> 16) & 1);   // RNE
  return (unsigned short)(r >> 16);
}
// fast sigmoid / tanh: native v_exp + v_rcp (~5 inst), saturate correctly
__device__ __forceinline__ float fsig(float x)  { return __fdividef(1.f, 1.f + __expf(-x)); }
__device__ __forceinline__ float ftanh(float x) { return 1.f - 2.f*__fdividef(1.f, __expf(2.f*x) + 1.f); }

// ---- workspace layout (float units; bf16 arrays are short* views) ----
constexpr int OFF_VIS   = 0;                               // fp32 [3][256][128]
constexpr int OFF_VISB  = 98304;                           // bf16 [3][256][128]
constexpr int OFF_MONB  = 147456;                          // bf16 [2][8192][128]
constexpr int OFF_TOTB  = 1196032;                         // bf16 [2][8192][128]
constexpr int OFF_W12T  = 2244608;                         // bf16 [8][128n][256k]
constexpr int OFF_WIHB  = 2375680;                         // bf16 [5][384n][128k]
constexpr int OFF_WIHTV = 2498560;                         // fp32 [4][128][384]
constexpr int OFF_XE    = 2695168;                         // fp32 [2][256][128]
constexpr int OFF_GI    = 2760704;                         // fp32 [8][8192][384]
constexpr int OFF_LAST  = 27926528;                        // fp32 [8][256][128]
constexpr int OFF_VGI   = 28188672;                        // fp32 [10][256][384]
constexpr int OFF_VH    = 29171712;                        // fp32 [10][16][128]

// =====================================================================
// prep: bf16 combined GNN weights (B^T layout), bf16 mgru Wih (B^T = as-is),
// fp32 vgru Wih transpose, weight/age xe
// =====================================================================
__global__ __launch_bounds__(256) void k_prep(
    const float* __restrict__ Wself, const float* __restrict__ Wmsg,
    const float* __restrict__ mWih,  const float* __restrict__ vWih,
    const float* __restrict__ wgt,   const float* __restrict__ age,
    const float* __restrict__ fwW,   const float* __restrict__ fwB,
    const float* __restrict__ faW,   const float* __restrict__ faB,
    short* __restrict__ w12t, short* __restrict__ wihb,
    float* __restrict__ wihTv, float* __restrict__ xe)
{
  int bx = blockIdx.x, tid = threadIdx.x;
  if (bx < 1024) {                      // w12t[pt][n][k] = bf16 combined
    int lin = bx*256 + tid;             // < 262144
    int pt = lin >> 15, rem = lin & 32767;
    int n = rem >> 8, k = rem & 255;
    float v;
    if (k < 128) v = Wself[pt*16384 + k*128 + n] - Wmsg[pt*16384 + k*128 + n]*(1.f/3.f);
    else         v = Wmsg[pt*16384 + (k-128)*128 + n]*(1.f/3.f);
    w12t[lin] = (short)f2bf(v);
  } else if (bx < 1984) {               // wihb = bf16(mWih) elementwise ([n][k] already)
    int lin = (bx-1024)*256 + tid;      // < 245760
    wihb[lin] = (short)f2bf(mWih[lin]);
  } else if (bx < 2752) {               // vgru Wih transpose fp32 (for k_vgi)
    int lin = (bx-1984)*256 + tid;      // < 196608
    int g = lin / 49152, rem2 = lin % 49152;
    int k = rem2 / 384, j = rem2 % 384;
    wihTv[lin] = vWih[g*49152 + j*128 + k];
  } else {                              // xe for weight / age
    int lin = (bx-2752)*256 + tid;      // < 65536
    int which = lin >> 15, rem2 = lin & 32767;
    int n = rem2 >> 7, d = rem2 & 127;
    float x  = which ? age[n] : wgt[n];
    float Wv = which ? faW[d] : fwW[d];
    float bb = which ? faB[d] : fwB[d];
    xe[lin] = (x != 0.0f) ? (x*Wv + bb) : 0.0f;
  }
}

// =====================================================================
// visit-event embedding sum pools: vis fp32 + visb bf16
// =====================================================================
__global__ __launch_bounds__(128) void k_vis(
    const int* __restrict__ cc, const int* __restrict__ cp, const int* __restrict__ cd,
    const float* __restrict__ ec, const float* __restrict__ ep, const float* __restrict__ ed,
    float* __restrict__ vis, short* __restrict__ visb)
{
  int type = blockIdx.x >> 8;
  int bv   = blockIdx.x & 255;
  int d    = threadIdx.x;
  const int*   codes = (type==0) ? cc : (type==1) ? cp : cd;
  const float* emb   = (type==0) ? ec : (type==1) ? ep : ed;
  float acc = 0.f;
  for (int c = 0; c < C_; ++c) {
    int code = codes[bv*C_ + c];
    acc += emb[code*D_ + d];
  }
  vis [(type*NSEQ + bv)*D_ + d] = acc;
  visb[(type*NSEQ + bv)*D_ + d] = (short)f2bf(acc);
}

// =====================================================================
// monitor-event pools -> bf16 feat (monb) and bf16 total (totb = mon + sum vis)
// =====================================================================
__global__ __launch_bounds__(128) void k_mon(
    const int* __restrict__ cli, const int* __restrict__ clv,
    const int* __restrict__ cii, const int* __restrict__ civ,
    const float* __restrict__ eli, const float* __restrict__ elv,
    const float* __restrict__ eii, const float* __restrict__ eiv,
    const float* __restrict__ vis,
    short* __restrict__ monb, short* __restrict__ totb)
{
  int p   = blockIdx.x >> 13;
  int bvm = blockIdx.x & 8191;
  int d   = threadIdx.x;
  const int* ci = p ? cii : cli;  const int* cv = p ? civ : clv;
  const float* ei = p ? eii : eli; const float* ev = p ? eiv : elv;
  float acc = 0.f;
  #pragma unroll
  for (int c = 0; c < CM_; ++c) {
    int iv = ci[bvm*CM_ + c];
    int vv = cv[bvm*CM_ + c];
    acc += ei[iv*D_ + d] * ev[vv*D_ + d];
  }
  int bv = bvm >> 5;
  float vsum = vis[bv*D_ + d] + vis[(NSEQ + bv)*D_ + d] + vis[(2*NSEQ + bv)*D_ + d];
  monb[(p*NROW + bvm)*D_ + d] = (short)f2bf(acc);
  totb[(p*NROW + bvm)*D_ + d] = (short)f2bf(acc + vsum);
}

// =====================================================================
// FUSED GNN+GI (MFMA bf16) — unchanged (verified).
// =====================================================================
__global__ __launch_bounds__(256, 2) void k_gg(
    const short* __restrict__ monb, const short* __restrict__ totb,
    const short* __restrict__ visb, const short* __restrict__ w12t,
    const short* __restrict__ wihb, const float* __restrict__ mbih,
    float* __restrict__ gi)
{
  const int pt = blockIdx.x >> 6;          // run 0..7
  const int rb = blockIdx.x & 63;
  const int p = pt >> 2, t = pt & 3;
  const int g = (pt % 4 == 0) ? (pt / 4) : (pt % 4 + 1);
  const int row0 = rb * 128;
  const int tid = threadIdx.x;
  const int w = tid >> 6, lane = tid & 63;
  const int c = lane & 15, q = lane >> 4;

  __shared__ short smem[2*128*72];         // 36864 B; Ys (128*136) aliases
  short (*Xs)[72]  = (short(*)[72])smem;
  short (*Ws)[72]  = (short(*)[72])(smem + 128*72);
  short (*Ys)[136] = (short(*)[136])smem;

  const int rowL = tid >> 1, kc = tid & 1;
  const int rowG = row0 + rowL;
  const int bv = rowG >> 5;
  const int mg = w >> 1, ng = w & 1;

  f32x4 acc1[4][4];
  #pragma unroll
  for (int mi = 0; mi < 4; ++mi)
    #pragma unroll
    for (int ni = 0; ni < 4; ++ni) acc1[mi][ni] = (f32x4){0.f,0.f,0.f,0.f};

  const short* featp = (t == 0) ? (monb + ((size_t)p*NROW + rowG)*128)
                                : (visb + ((size_t)(t-1)*NSEQ + bv)*128);
  const short* totp  = totb + ((size_t)p*NROW + rowG)*128;
  const short* wrow  = w12t + ((size_t)pt*128 + rowL)*256;

  #pragma unroll 1
  for (int ks = 0; ks < 4; ++ks) {
    __syncthreads();
    int kg = ks*64 + kc*32;
    const short* srcX = (kg < 128) ? (featp + kg) : (totp + (kg - 128));
    const short* srcW = wrow + kg;
    short* dX = &Xs[rowL][kc*32];
    short* dW = &Ws[rowL][kc*32];
    #pragma unroll
    for (int i = 0; i < 4; ++i) {
      *(bf16x8*)(dX + 8*i) = *(const bf16x8*)(srcX + 8*i);
      *(bf16x8*)(dW + 8*i) = *(const bf16x8*)(srcW + 8*i);
    }
    __syncthreads();
    #pragma unroll
    for (int kk = 0; kk < 2; ++kk) {
      bf16x8 af[4], bfr[4];
      #pragma unroll
      for (int mi = 0; mi < 4; ++mi)
        af[mi] = *(const bf16x8*)&Xs[(mg*4+mi)*16 + c][kk*32 + q*8];
      #pragma unroll
      for (int ni = 0; ni < 4; ++ni)
        bfr[ni] = *(const bf16x8*)&Ws[(ng*4+ni)*16 + c][kk*32 + q*8];
      #pragma unroll
      for (int mi = 0; mi < 4; ++mi)
        #pragma unroll
        for (int ni = 0; ni < 4; ++ni)
          acc1[mi][ni] = __builtin_amdgcn_mfma_f32_16x16x32_bf16(af[mi], bfr[ni], acc1[mi][ni], 0, 0, 0);
    }
  }
  __syncthreads();     // done reading Xs/Ws (Ys aliases them)

  // relu + C-layout (col=lane&15, row=(lane>>4)*4+reg) -> Ys[row][col] bf16
  #pragma unroll
  for (int mi = 0; mi < 4; ++mi)
    #pragma unroll
    for (int ni = 0; ni < 4; ++ni)
      #pragma unroll
      for (int reg = 0; reg < 4; ++reg)
        Ys[(mg*4+mi)*16 + q*4 + reg][(ng*4+ni)*16 + c] =
            (short)f2bf(fmaxf(acc1[mi][ni][reg], 0.f));
  __syncthreads();

  // ---- stage 2: gi = Y @ Wih^T + bih ----
  bf16x8 Af[2][4];
  #pragma unroll
  for (int mi = 0; mi < 2; ++mi)
    #pragma unroll
    for (int kt = 0; kt < 4; ++kt)
      Af[mi][kt] = *(const bf16x8*)&Ys[(w*2+mi)*16 + c][kt*32 + q*8];

  float bihv[24];
  #pragma unroll
  for (int nt = 0; nt < 24; ++nt)
    bihv[nt] = mbih[g*384 + nt*16 + c];

  float* gout = gi + ((size_t)pt*NROW + row0)*384;
  #pragma unroll 1
  for (int cn = 0; cn < 6; ++cn) {
    f32x4 acc2[2][4];
    #pragma unroll
    for (int mi = 0; mi < 2; ++mi)
      #pragma unroll
      for (int ni = 0; ni < 4; ++ni) acc2[mi][ni] = (f32x4){0.f,0.f,0.f,0.f};
    #pragma unroll
    for (int ni = 0; ni < 4; ++ni) {
      int n = (cn*4 + ni)*16 + c;
      const short* bp_ = wihb + ((size_t)g*384 + n)*128 + q*8;
      #pragma unroll
      for (int kt = 0; kt < 4; ++kt) {
        bf16x8 bfr = *(const bf16x8*)(bp_ + kt*32);
        #pragma unroll
        for (int mi = 0; mi < 2; ++mi)
          acc2[mi][ni] = __builtin_amdgcn_mfma_f32_16x16x32_bf16(Af[mi][kt], bfr, acc2[mi][ni], 0, 0, 0);
      }
    }
    #pragma unroll
    for (int mi = 0; mi < 2; ++mi)
      #pragma unroll
      for (int ni = 0; ni < 4; ++ni) {
        int col = (cn*4+ni)*16 + c;
        float bia = bihv[cn*4+ni];
        #pragma unroll
        for (int reg = 0; reg < 4; ++reg) {
          int row = (w*2+mi)*16 + q*4 + reg;
          gout[(size_t)row*384 + col] = acc2[mi][ni][reg] + bia;
        }
      }
  }
}

// =====================================================================
// monitor-level GRU v5 (MFMA): v4 + fast gates (native exp/rcp) + true
// double-buffered gi prefetch (alternating gA/gB, unrolled x2 — the load
// wait slides past the next step's MFMA instead of stalling in-step).
// =====================================================================
__global__ __launch_bounds__(256, 1) void k_mgru(
    const float* __restrict__ gi, const float* __restrict__ mWhh,
    const float* __restrict__ mbhh, float* __restrict__ last)
{
  const int run = blockIdx.x >> 5, grp = blockIdx.x & 31;
  const int g = (run % 4 == 0) ? (run / 4) : (run % 4 + 1);
  const int tid = threadIdx.x;
  const int w = tid >> 6;
  const int lane = tid & 63;
  const int c = lane & 15, q = lane >> 4;

  __shared__ short hb[2][4][16][40];

  for (int idx = tid; idx < 2*4*16*40; idx += 256)
    ((short*)hb)[idx] = 0;

  bf16x8 bfrag[2][3][4];
  #pragma unroll
  for (int jj = 0; jj < 2; ++jj)
    #pragma unroll
    for (int gate = 0; gate < 3; ++gate) {
      int n = (w + jj*4 + gate*8)*16 + c;
      const float* wp = mWhh + (g*384 + n)*128 + q*8;
      #pragma unroll
      for (int kt = 0; kt < 4; ++kt) {
        float4 lo = *(const float4*)(wp + kt*32);
        float4 hi = *(const float4*)(wp + kt*32 + 4);
        bf16x8 t;
        t[0]=(short)f2bf(lo.x); t[1]=(short)f2bf(lo.y); t[2]=(short)f2bf(lo.z); t[3]=(short)f2bf(lo.w);
        t[4]=(short)f2bf(hi.x); t[5]=(short)f2bf(hi.y); t[6]=(short)f2bf(hi.z); t[7]=(short)f2bf(hi.w);
        bfrag[jj][gate][kt] = t;
      }
    }

  const int j0 = w*16 + c;
  const int j1 = (w+4)*16 + c;
  const float* bh = mbhh + g*384;
  float bh_[2][3];
  bh_[0][0]=bh[j0]; bh_[0][1]=bh[j0+128]; bh_[0][2]=bh[j0+256];
  bh_[1][0]=bh[j1]; bh_[1][1]=bh[j1+128]; bh_[1][2]=bh[j1+256];

  float hf[2][4] = {{0.f,0.f,0.f,0.f},{0.f,0.f,0.f,0.f}};
  const float* gib = gi + ((size_t)run*NROW + grp*8*32)*384;
  const bool act = (lane < 32);

  float gA[2][3][4], gB[2][3][4];
  if (act) {
    #pragma unroll
    for (int jj = 0; jj < 2; ++jj) {
      int j = jj ? j1 : j0;
      #pragma unroll
      for (int gate = 0; gate < 3; ++gate)
        #pragma unroll
        for (int reg = 0; reg < 4; ++reg)
          gA[jj][gate][reg] = gib[((q*4+reg)*32 + 0)*384 + gate*128 + j];
    }
  }
  __syncthreads();

  auto dostep = [&](int m, float (&gcur)[2][3][4], float (&gnext)[2][3][4]) {
    const int cur = m & 1, nxt = cur ^ 1;
    bf16x8 a[4];
    #pragma unroll
    for (int kt = 0; kt < 4; ++kt)
      a[kt] = *(const bf16x8*)&hb[cur][kt][c][q*8];

    f32x4 acc[2][3];
    #pragma unroll
    for (int jj = 0; jj < 2; ++jj)
      #pragma unroll
      for (int gate = 0; gate < 3; ++gate) {
        f32x4 t = {0.f,0.f,0.f,0.f};
        #pragma unroll
        for (int kt = 0; kt < 4; ++kt)
          t = __builtin_amdgcn_mfma_f32_16x16x32_bf16(a[kt], bfrag[jj][gate][kt], t, 0, 0, 0);
        acc[jj][gate] = t;
      }

    if (act && m < 31) {
      #pragma unroll
      for (int jj = 0; jj < 2; ++jj) {
        int j = jj ? j1 : j0;
        #pragma unroll
        for (int gate = 0; gate < 3; ++gate)
          #pragma unroll
          for (int reg = 0; reg < 4; ++reg)
            gnext[jj][gate][reg] = gib[((q*4+reg)*32 + (m+1))*384 + gate*128 + j];
      }
    }

    if (act) {
      #pragma unroll
      for (int jj = 0; jj < 2; ++jj) {
        int j = jj ? j1 : j0;
        int kt = j >> 5, kk = j & 31;
        #pragma unroll
        for (int reg = 0; reg < 4; ++reg) {
          int row = q*4 + reg;
          float rr = fsig(acc[jj][0][reg] + bh_[jj][0] + gcur[jj][0][reg]);
          float zz = fsig(acc[jj][1][reg] + bh_[jj][1] + gcur[jj][1][reg]);
          float nn = ftanh(gcur[jj][2][reg] + rr*(acc[jj][2][reg] + bh_[jj][2]));
          float hnew = (1.f - zz)*nn + zz*hf[jj][reg];
          hf[jj][reg] = hnew;
          hb[nxt][kt][row][kk] = (short)f2bf(hnew);
        }
      }
    }
    __syncthreads();
  };

  #pragma unroll 1
  for (int m2 = 0; m2 < 16; ++m2) {
    dostep(2*m2,     gA, gB);
    dostep(2*m2 + 1, gB, gA);
  }

  if (act) {
    #pragma unroll
    for (int jj = 0; jj < 2; ++jj) {
      int j = jj ? j1 : j0;
      #pragma unroll
      for (int reg = 0; reg < 4; ++reg)
        last[(run*NSEQ + grp*8 + q*4 + reg)*D_ + j] = hf[jj][reg];
    }
  }
}

// =====================================================================
// visit-level gi precompute (small GEMM), 10 runs x 256 rows
// =====================================================================
__global__ __launch_bounds__(384) void k_vgi(
    const float* __restrict__ last, const float* __restrict__ xe,
    const float* __restrict__ wihTv, const float* __restrict__ vbih,
    float* __restrict__ vgi)
{
  int run = blockIdx.x >> 5;
  int rblk = blockIdx.x & 31;
  int j = threadIdx.x;
  int vidx = (run < 4) ? 0 : (run < 8) ? 1 : (run - 6);
  __shared__ float Xs[8][128];
  const float* X = (run < 8) ? (last + run*NSEQ*D_) : (xe + (run-8)*NSEQ*D_);
  for (int idx = j; idx < 1024; idx += 384) {
    int s = idx >> 7, k = idx & 127;
    Xs[s][k] = X[(rblk*8 + s)*D_ + k];
  }
  __syncthreads();
  float acc[8];
  float bias = vbih[vidx*384 + j];
  #pragma unroll
  for (int s = 0; s < 8; ++s) acc[s] = bias;
  const float* W = wihTv + vidx*49152 + j;
  #pragma unroll 4
  for (int k = 0; k < 128; ++k) {
    float wv = W[k*384];
    #pragma unroll
    for (int s = 0; s < 8; ++s) acc[s] += Xs[s][k] * wv;
  }
  #pragma unroll
  for (int s = 0; s < 8; ++s)
    vgi[(run*NSEQ + rblk*8 + s)*384 + j] = acc[s];
}

// =====================================================================
// visit-level GRU v2.2: fast gates (native exp/rcp); structure unchanged.
// =====================================================================
__global__ __launch_bounds__(768) void k_vgru(
    const float* __restrict__ vgi, const float* __restrict__ vWhh,
    const float* __restrict__ vbhh, float* __restrict__ vh)
{
  int run = blockIdx.x >> 4, b = blockIdx.x & 15;
  int tid = threadIdx.x;
  int j = tid >> 1, kh = tid & 1;
  int vidx = (run < 4) ? 0 : (run < 8) ? 1 : (run - 6);
  float w[64];
  const float4* wrow = (const float4*)(vWhh + (vidx*384 + j)*128 + kh*64);
  #pragma unroll
  for (int k4 = 0; k4 < 16; ++k4) {
    float4 t4 = wrow[k4];
    w[4*k4] = t4.x; w[4*k4+1] = t4.y; w[4*k4+2] = t4.z; w[4*k4+3] = t4.w;
  }
  float bj = vbhh[vidx*384 + j];
  __shared__ __align__(16) float hsv[128];
  __shared__ float gh[384];
  if (tid < 128) hsv[tid] = 0.f;
  __syncthreads();
  const float* gib = vgi + (run*NSEQ + b*16)*384;
  #pragma unroll 1
  for (int v = 0; v < 16; ++v) {
    const float4* h4 = (const float4*)(hsv + kh*64);
    float p0 = 0.f, p1 = 0.f;
    #pragma unroll
    for (int k4 = 0; k4 < 8; ++k4) {
      float4 u0 = h4[k4], u1 = h4[k4+8];
      p0 += w[4*k4   ]*u0.x + w[4*k4+1 ]*u0.y + w[4*k4+2 ]*u0.z + w[4*k4+3 ]*u0.w;
      p1 += w[4*k4+32]*u1.x + w[4*k4+33]*u1.y + w[4*k4+34]*u1.z + w[4*k4+35]*u1.w;
    }
    float part = p0 + p1;
    part += __shfl_xor(part, 1);
    if (kh == 0) gh[j] = bj + ((j < 256) ? gib[v*384 + j] : 0.f) + part;
    __syncthreads();
    if (tid < 128) {
      float r = fsig(gh[tid]);
      float z = fsig(gh[tid+128]);
      float gin = gib[v*384 + 256 + tid];
      float n = ftanh(gin + r*gh[tid+256]);
      hsv[tid] = (1.f - z)*n + z*hsv[tid];
    }
    __syncthreads();
  }
  if (tid < 128) vh[(run*16 + b)*D_ + tid] = hsv[tid];
}

// =====================================================================
// head v2 — unchanged (verified).
// =====================================================================
__global__ __launch_bounds__(256) void k_head(
    const float* __restrict__ vh, const float* __restrict__ Wp,
    const float* __restrict__ bp, float* __restrict__ out)
{
  const int o = blockIdx.x;
  const int tid = threadIdx.x;
  __shared__ float peL[16*899];
  __shared__ float wL[896];
  __shared__ float red[16][17];

  const int a1[7] = {0,1,2,3,4,8,9};
  const int a2[7] = {-1,5,6,7,-1,-1,-1};

  for (int idx = tid; idx < 16*896; idx += 256) {
    int b = idx / 896, cc2 = idx % 896;
    int s = cc2 >> 7, d = cc2 & 127;
    float v = vh[(a1[s]*16 + b)*D_ + d];
    int s2 = a2[s];
    if (s2 >= 0) v += vh[(s2*16 + b)*D_ + d];
    peL[b*899 + cc2] = fmaxf(v, 0.f);
  }
  for (int idx = tid; idx < 896; idx += 256)
    wL[idx] = Wp[o*896 + idx];
  __syncthreads();

  const int b = tid & 15, kc = tid >> 4;
  const float* pb = peL + b*899 + kc*56;
  const float* wb = wL + kc*56;
  float acc = 0.f;
  #pragma unroll
  for (int i = 0; i < 56; ++i)
    acc += pb[i] * wb[i];
  red[kc][b] = acc;
  __syncthreads();
  if (tid < 16) {
    float s = 0.f;
    #pragma unroll
    for (int k = 0; k < 16; ++k) s += red[k][tid];
    out[tid*OUT_ + o] = s + bp[o];
  }
}

// =====================================================================
extern "C" void kernel_launch(void* const* d_in, const int* in_sizes, int n_in,
                              void* d_out, int out_size, void* d_ws, size_t ws_size,
                              hipStream_t stream)
{
  (void)in_sizes; (void)n_in; (void)out_size; (void)ws_size;
  const int*   cc   = (const int*)  d_in[0];
  const int*   cp   = (const int*)  d_in[1];
  const int*   cd   = (const int*)  d_in[2];
  const int*   cli  = (const int*)  d_in[3];
  const int*   clv  = (const int*)  d_in[4];
  const int*   cii  = (const int*)  d_in[5];
  const int*   civ  = (const int*)  d_in[6];
  const float* wgt  = (const float*)d_in[7];
  const float* age  = (const float*)d_in[8];
  const float* ec   = (const float*)d_in[9];
  const float* ep   = (const float*)d_in[10];
  const float* ed   = (const float*)d_in[11];
  const float* eli  = (const float*)d_in[12];
  const float* elv  = (const float*)d_in[13];
  const float* eii  = (const float*)d_in[14];
  const float* eiv  = (const float*)d_in[15];
  const float* mWih = (const float*)d_in[16];
  const float* mWhh = (const float*)d_in[17];
  const float* mbih = (const float*)d_in[18];
  const float* mbhh = (const float*)d_in[19];
  const float* vWih = (const float*)d_in[20];
  const float* vWhh = (const float*)d_in[21];
  const float* vbih = (const float*)d_in[22];
  const float* vbhh = (const float*)d_in[23];
  const float* Wself= (const float*)d_in[24];
  const float* Wmsg = (const float*)d_in[25];
  const float* fwW  = (const float*)d_in[26];
  const float* fwB  = (const float*)d_in[27];
  const float* faW  = (const float*)d_in[28];
  const float* faB  = (const float*)d_in[29];
  const float* Wp   = (const float*)d_in[30];
  const float* bp   = (const float*)d_in[31];
  float* out = (float*)d_out;
  float* ws  = (float*)d_ws;

  float* vis   = ws + OFF_VIS;
  short* visb  = (short*)(ws + OFF_VISB);
  short* monb  = (short*)(ws + OFF_MONB);
  short* totb  = (short*)(ws + OFF_TOTB);
  short* w12t  = (short*)(ws + OFF_W12T);
  short* wihb  = (short*)(ws + OFF_WIHB);
  float* wihTv = ws + OFF_WIHTV;
  float* xe    = ws + OFF_XE;
  float* gi    = ws + OFF_GI;
  float* last  = ws + OFF_LAST;
  float* vgi   = ws + OFF_VGI;
  float* vh    = ws + OFF_VH;

  k_prep<<<3008, 256, 0, stream>>>(Wself, Wmsg, mWih, vWih, wgt, age,
                                   fwW, fwB, faW, faB, w12t, wihb, wihTv, xe);
  k_vis <<<768, 128, 0, stream>>>(cc, cp, cd, ec, ep, ed, vis, visb);
  k_mon <<<16384, 128, 0, stream>>>(cli, clv, cii, civ, eli, elv, eii, eiv,
                                    vis, monb, totb);
  k_gg  <<<512, 256, 0, stream>>>(monb, totb, visb, w12t, wihb, mbih, gi);
  k_mgru<<<256, 256, 0, stream>>>(gi, mWhh, mbhh, last);
  k_vgi <<<320, 384, 0, stream>>>(last, xe, wihTv, vbih, vgi);
  k_vgru<<<160, 768, 0, stream>>>(vgi, vWhh, vbhh, vh);
  k_head<<<600, 256, 0, stream>>>(vh, Wp, bp, out);
}